// Round 9
// baseline (977.688 us; speedup 1.0000x reference)
//
#include <hip/hip_runtime.h>
#include <stdint.h>

#define DEVFN static __device__ __forceinline__

typedef unsigned short u16;
typedef unsigned long long u64;
typedef short short8 __attribute__((ext_vector_type(8)));
typedef float vf4 __attribute__((ext_vector_type(4)));

constexpr int B = 2048;
constexpr int DIN = 768;
constexpr int D = 32768;
constexpr int NDI = B * D;                 // 67,108,864
constexpr unsigned TOPK_TOTAL = 65536u;    // 32 * B
constexpr int TOPK_AUX = 512;
constexpr int ROWCAP = 512;
constexpr int CANDCAP = 3145728;           // candidates with v>=1.0 (~2.38M measured-model)
constexpr int GSTAGE = 2048;               // per-GEMM-block LDS cand stage
constexpr int CSTAGE = 4096;
constexpr int TIECAP = 4096;
constexpr int SCAP = 3072;                 // aux boundary-bin LDS stage cap
constexpr int NREP = 16;                   // global histogram replicas

// ---------------- workspace layout (bytes) ----------------
constexpr size_t OFF_HIST1  = 0;                          // 16 x 8192 (level-1, from GEMM)
constexpr size_t OFF_HIST2  = 131072;                     // 16 x 8192 (fallback full hist)
constexpr size_t OFF_HIST3  = 262144;                     // 16 x 8192 (refine level-2)
constexpr size_t OFF_HIST4  = 393216;                     // 16 x 4096 (refine level-3)
constexpr size_t OFF_SCALU  = 458752;                     // u32[64]
constexpr size_t OFF_SCALD  = 459008;                     // double[32]
constexpr size_t OFF_ROWCNT = 459264;                     // 8192
constexpr size_t OFF_AUXCNT = 467456;                     // 8192
constexpr size_t OFF_COLACT = 475648;                     // 131072
constexpr size_t ZERO_BYTES = 606720;
constexpr size_t OFF_XN    = ZERO_BYTES;                  // 6291456
constexpr size_t OFF_RES   = OFF_XN   + 6291456;          // 6291456
constexpr size_t OFF_RMEAN = OFF_RES  + 6291456;          // 8192
constexpr size_t OFF_RSTD  = OFF_RMEAN + 8192;            // 8192
constexpr size_t OFF_XNCB  = OFF_RSTD + 8192;             // 3145728 (bf16 xnc)
constexpr size_t OFF_DEAD  = OFF_XNCB + 3145728;          // 131072
constexpr size_t OFF_DMASK = OFF_DEAD + 131072;           // 4096  (512 x u64 dead bitmask)
constexpr size_t OFF_DBASE = OFF_DMASK + 4096;            // 2048  (512 x u32 prefix base)
constexpr size_t OFF_RLC   = OFF_DBASE + 2048;            // 4194304
constexpr size_t OFF_RLV   = OFF_RLC  + 4194304;          // 4194304
constexpr size_t OFF_AXC   = OFF_RLV  + 4194304;          // 4194304
constexpr size_t OFF_AXV   = OFF_AXC  + 4194304;          // 4194304
constexpr size_t OFF_CANDI = OFF_AXV  + 4194304;          // 12582912
constexpr size_t OFF_CANDV = OFF_CANDI + (size_t)CANDCAP * 4; // 12582912
constexpr size_t OFF_TIEB  = OFF_CANDV + (size_t)CANDCAP * 4; // 16384
constexpr size_t OFF_WT    = OFF_TIEB + (size_t)TIECAP * 4;   // 50331648 (WencT bf16; reused as Wdec bf16)

// scalU: 0 b1, 1 cntgt1, 2 b2, 3 cntgt2, 4 cutoff_bits, 5 cntgt_final, 6 need,
//        7 tie_thr(i32), 9 l0_count, 10 n_dead, 11 num_dead_feat, 12 cand_count,
//        13 needFull, 14 tie_count
// scalD: 0 l1_sum, 1 sum_xn, 2 sumsq_xn, 3 sq0, 4..8 group_sq[5], 9 aux_sq, 10 aux_abs

DEVFN u16 f2bf(float f) {
  unsigned u = __float_as_uint(f);
  unsigned r = (u + 0x7FFFu + ((u >> 16) & 1u)) >> 16;
  return (u16)r;
}
DEVFN float b2f(u16 h) { return __uint_as_float(((unsigned)h) << 16); }

DEVFN float bsumf(float v, float* red) {
  int t = threadIdx.x;
  red[t] = v; __syncthreads();
  for (int o = 128; o > 0; o >>= 1) { if (t < o) red[t] += red[t + o]; __syncthreads(); }
  float r = red[0]; __syncthreads();
  return r;
}
DEVFN unsigned bsumu(unsigned v, unsigned* red) {
  int t = threadIdx.x;
  red[t] = v; __syncthreads();
  for (int o = 128; o > 0; o >>= 1) { if (t < o) red[t] += red[t + o]; __syncthreads(); }
  unsigned r = red[0]; __syncthreads();
  return r;
}

// Find bin (scanning from the top) where cumulative count reaches K.
DEVFN void findBin(const unsigned* hist, int nb, unsigned K, unsigned base,
                   unsigned* sscan, int* s_b, unsigned* s_cnt)
{
  int t = threadIdx.x;
  int chunk = nb >> 8;
  int hi = nb - 1 - t * chunk;
  unsigned p = 0;
  for (int k = 0; k < chunk; ++k) p += hist[hi - k];
  sscan[t] = p; __syncthreads();
  for (int o = 1; o < 256; o <<= 1) {
    unsigned xx = (t >= o) ? sscan[t - o] : 0u; __syncthreads();
    sscan[t] += xx; __syncthreads();
  }
  unsigned incl = sscan[t], excl = incl - p;
  unsigned cum = base + excl;
  if (base + incl >= K && cum < K) {
    unsigned acc = cum;
    for (int k = 0; k < chunk; ++k) {
      unsigned h = hist[hi - k];
      if (acc + h >= K) { *s_b = hi - k; *s_cnt = acc; break; }
      acc += h;
    }
  }
  __syncthreads();
}

// -------- row stats + normalization (+ bf16 xnc) --------
__global__ __launch_bounds__(256) void k_rowstats(
    const float* __restrict__ x, const float* __restrict__ bdec,
    float* __restrict__ xn, u16* __restrict__ xncb,
    float* __restrict__ rmean, float* __restrict__ rstd, double* scalD)
{
  __shared__ float red[256];
  const int row = blockIdx.x, t = threadIdx.x;
  const float* xr = x + (size_t)row * DIN;
  float v0 = xr[t], v1 = xr[t + 256], v2 = xr[t + 512];
  float mean = bsumf(v0 + v1 + v2, red) * (1.0f / DIN);
  float d0 = v0 - mean, d1 = v1 - mean, d2 = v2 - mean;
  float var = bsumf(d0 * d0 + d1 * d1 + d2 * d2, red) * (1.0f / (DIN - 1));
  float sd = sqrtf(var);
  float inv = 1.0f / (sd + 1e-5f);
  float n0 = d0 * inv, n1 = d1 * inv, n2 = d2 * inv;
  size_t o = (size_t)row * DIN;
  xn[o + t] = n0; xn[o + t + 256] = n1; xn[o + t + 512] = n2;
  float b0 = bdec[t], b1 = bdec[t + 256], b2 = bdec[t + 512];
  xncb[o + t] = f2bf(n0 - b0); xncb[o + t + 256] = f2bf(n1 - b1); xncb[o + t + 512] = f2bf(n2 - b2);
  if (t == 0) { rmean[row] = mean; rstd[row] = sd; }
  float sxn = bsumf(n0 + n1 + n2, red);
  float ssq = bsumf(n0 * n0 + n1 * n1 + n2 * n2, red);
  float e0 = b0 - n0, e1 = b1 - n1, e2 = b2 - n2;
  float sq0 = bsumf(e0 * e0 + e1 * e1 + e2 * e2, red);
  if (t == 0) {
    atomicAdd(&scalD[1], (double)sxn);
    atomicAdd(&scalD[2], (double)ssq);
    atomicAdd(&scalD[3], (double)sq0);
  }
}

// -------- W_enc [768][32768] f32 -> Wt [32768][768] bf16 (transpose+convert) --------
__global__ __launch_bounds__(256) void k_wt(const float* __restrict__ W, u16* __restrict__ Wt)
{
  __shared__ float tl[64][65];
  const int t = threadIdx.x;
  const int n0 = blockIdx.x * 64, k0 = blockIdx.y * 64;
  const int rr = t >> 6, cc = t & 63;
#pragma unroll
  for (int r = 0; r < 16; ++r) {
    int kk = r * 4 + rr;
    tl[kk][cc] = W[(size_t)(k0 + kk) * D + n0 + cc];
  }
  __syncthreads();
#pragma unroll
  for (int r = 0; r < 16; ++r) {
    int nn = r * 4 + rr;
    Wt[(size_t)(n0 + nn) * DIN + k0 + cc] = f2bf(tl[cc][nn]);
  }
}

// -------- W_dec [32768][768] f32 -> bf16 (elementwise) --------
__global__ __launch_bounds__(256) void k_wdecb(const float4* __restrict__ W4, u16* __restrict__ Wb)
{
  int stride = gridDim.x * blockDim.x;
  const int n4 = (D * DIN) / 4;
  for (int i = blockIdx.x * 256 + threadIdx.x; i < n4; i += stride) {
    float4 f = W4[i];
    unsigned p0 = (unsigned)f2bf(f.x) | ((unsigned)f2bf(f.y) << 16);
    unsigned p1 = (unsigned)f2bf(f.z) | ((unsigned)f2bf(f.w) << 16);
    uint2 q; q.x = p0; q.y = p1;
    *(uint2*)&Wb[(size_t)i * 4] = q;
  }
}

// -------- encode GEMM: acts = relu(xnc @ Wenc), bf16 MFMA + hist + cand compact --------
// Grid: (B/128, D/128) with bm on x (fast) so consecutive blocks share one Bt tile (L2).
__global__ __launch_bounds__(256) void k_gemm(const u16* __restrict__ A,
                                              const u16* __restrict__ Bt,
                                              float* __restrict__ C,
                                              unsigned* __restrict__ hist16,
                                              unsigned* __restrict__ scalU,
                                              unsigned* __restrict__ candI,
                                              float* __restrict__ candV)
{
  __shared__ __align__(16) char lds[32768];
  __shared__ unsigned sCnt, sBase;
  const int tid = threadIdx.x, lane = tid & 63, wid = tid >> 6;
  const int bm = blockIdx.x * 128, bn = blockIdx.y * 128;

  const char* pA[4]; const char* pB[4];
#pragma unroll
  for (int i = 0; i < 4; ++i) {
    int G = i * 256 + wid * 64 + lane;
    int r = G >> 3, c = (G & 7) ^ (r & 7);
    pA[i] = (const char*)(A + (size_t)(bm + r) * DIN + c * 8);
    pB[i] = (const char*)(Bt + (size_t)(bn + r) * DIN + c * 8);
  }
  int aoff[2][4], boff[2][4];
#pragma unroll
  for (int kc = 0; kc < 2; ++kc)
#pragma unroll
    for (int i = 0; i < 4; ++i) {
      int cs = kc * 4 + (lane >> 4);
      int rA = (wid >> 1) * 64 + i * 16 + (lane & 15);
      aoff[kc][i] = rA * 128 + ((cs ^ (rA & 7)) * 16);
      int rB = (wid & 1) * 64 + i * 16 + (lane & 15);
      boff[kc][i] = 16384 + rB * 128 + ((cs ^ (rB & 7)) * 16);
    }

  vf4 acc[4][4];
#pragma unroll
  for (int i = 0; i < 4; ++i)
#pragma unroll
    for (int j = 0; j < 4; ++j) acc[i][j] = (vf4)0.f;

  for (int ks = 0; ks < 12; ++ks) {
    __syncthreads();
#pragma unroll
    for (int i = 0; i < 4; ++i) {
      __builtin_amdgcn_global_load_lds(
          (const __attribute__((address_space(1))) void*)pA[i],
          (__attribute__((address_space(3))) void*)(lds + (i * 256 + wid * 64) * 16), 16, 0, 0);
      __builtin_amdgcn_global_load_lds(
          (const __attribute__((address_space(1))) void*)pB[i],
          (__attribute__((address_space(3))) void*)(lds + 16384 + (i * 256 + wid * 64) * 16), 16, 0, 0);
      pA[i] += 128; pB[i] += 128;
    }
    __syncthreads();
#pragma unroll
    for (int kc = 0; kc < 2; ++kc) {
      short8 av[4], bv[4];
#pragma unroll
      for (int i = 0; i < 4; ++i) {
        av[i] = *(const short8*)(lds + aoff[kc][i]);
        bv[i] = *(const short8*)(lds + boff[kc][i]);
      }
#pragma unroll
      for (int i = 0; i < 4; ++i)
#pragma unroll
        for (int j = 0; j < 4; ++j)
          acc[i][j] = __builtin_amdgcn_mfma_f32_16x16x32_bf16(av[i], bv[j], acc[i][j], 0, 0, 0);
    }
  }

  // epilogue: LDS reused as hist (8KB) + candidate stage (16KB)
  unsigned* h = (unsigned*)lds;
  unsigned* stIdx = (unsigned*)(lds + 8192);
  float* stVal = (float*)(lds + 16384);
  __syncthreads();
  for (int j = tid; j < 2048; j += 256) h[j] = 0;
  if (tid == 0) sCnt = 0;
  __syncthreads();

  const int r0 = bm + (wid >> 1) * 64 + (lane >> 4) * 4;
  const int c0 = bn + (wid & 1) * 64 + (lane & 15);
#pragma unroll
  for (int i = 0; i < 4; ++i)
#pragma unroll
    for (int j = 0; j < 4; ++j) {
      float* cp = C + (size_t)(r0 + i * 16) * D + c0 + j * 16;
#pragma unroll
      for (int q = 0; q < 4; ++q) {
        float v = fmaxf(acc[i][j][q], 0.f);
        cp[(size_t)q * D] = v;
        if (v >= 1.0f) {
          atomicAdd(&h[__float_as_uint(v) >> 21], 1u);
          unsigned idx = ((unsigned)(r0 + i * 16 + q) << 15) | (unsigned)(c0 + j * 16);
          unsigned p = atomicAdd(&sCnt, 1u);
          if (p < (unsigned)GSTAGE) { stIdx[p] = idx; stVal[p] = v; }
          else {
            unsigned g = atomicAdd(&scalU[12], 1u);
            if (g < (unsigned)CANDCAP) { candI[g] = idx; candV[g] = v; }
          }
        }
      }
    }
  __syncthreads();
  unsigned* dst = hist16 + (size_t)(blockIdx.x & (NREP - 1)) * 2048;
  for (int j = 508 + tid; j < 2048; j += 256) {
    unsigned c = h[j];
    if (c) atomicAdd(&dst[j], c);
  }
  unsigned n = sCnt < (unsigned)GSTAGE ? sCnt : (unsigned)GSTAGE;
  if (tid == 0) sBase = atomicAdd(&scalU[12], n);
  __syncthreads();
  unsigned base = sBase;
  for (unsigned jj = tid; jj < n; jj += 256) {
    unsigned g = base + jj;
    if (g < (unsigned)CANDCAP) { candI[g] = stIdx[jj]; candV[g] = stVal[jj]; }
  }
}

// -------- scan over thresholded histogram; detect fallback need --------
__global__ __launch_bounds__(256) void k_scan1a(unsigned* scalU, const unsigned* __restrict__ h16)
{
  __shared__ unsigned hsum[2048];
  __shared__ unsigned sscan[256];
  __shared__ int s_b; __shared__ unsigned s_cnt;
  int t = threadIdx.x;
  for (int j = t; j < 2048; j += 256) {
    unsigned s = 0;
#pragma unroll
    for (int r = 0; r < NREP; ++r) s += h16[r * 2048 + j];
    hsum[j] = s;
  }
  if (t == 0) { s_b = 0; s_cnt = 0; }
  __syncthreads();
  unsigned p = 0;
  for (int j = 508 + t; j < 2048; j += 256) p += hsum[j];
  unsigned total = bsumu(p, sscan);
  if (total >= TOPK_TOTAL) {
    findBin(hsum, 2048, TOPK_TOTAL, 0u, sscan, &s_b, &s_cnt);
    if (t == 0) { scalU[0] = (unsigned)s_b; scalU[1] = s_cnt; scalU[13] = 0u; }
  } else if (t == 0) { scalU[13] = 1u; scalU[12] = 0u; }  // rebuild cand list in fallback
}

// -------- fallback: full positive histogram (normally immediate-return) --------
__global__ __launch_bounds__(256) void k_histfull(const float4* __restrict__ a4,
    const unsigned* __restrict__ scalU, unsigned* __restrict__ h16)
{
  if (scalU[13] == 0u) return;
  __shared__ unsigned lh[4][2048];
  for (int j = threadIdx.x; j < 8192; j += 256) ((unsigned*)lh)[j] = 0;
  __syncthreads();
  unsigned* mylh = lh[threadIdx.x & 3];
  int stride = gridDim.x * blockDim.x;
  for (int i = blockIdx.x * 256 + threadIdx.x; i < NDI / 4; i += stride) {
    float4 f = a4[i];
    if (f.x > 0.f) atomicAdd(&mylh[__float_as_uint(f.x) >> 21], 1u);
    if (f.y > 0.f) atomicAdd(&mylh[__float_as_uint(f.y) >> 21], 1u);
    if (f.z > 0.f) atomicAdd(&mylh[__float_as_uint(f.z) >> 21], 1u);
    if (f.w > 0.f) atomicAdd(&mylh[__float_as_uint(f.w) >> 21], 1u);
  }
  __syncthreads();
  unsigned* dst = h16 + (size_t)(blockIdx.x & (NREP - 1)) * 2048;
  for (int j = threadIdx.x; j < 2048; j += 256) {
    unsigned c = lh[0][j] + lh[1][j] + lh[2][j] + lh[3][j];
    if (c) atomicAdd(&dst[j], c);
  }
}

__global__ __launch_bounds__(256) void k_scan1b(unsigned* scalU, const unsigned* __restrict__ h16)
{
  if (scalU[13] == 0u) return;
  __shared__ unsigned hsum[2048];
  __shared__ unsigned sscan[256];
  __shared__ int s_b; __shared__ unsigned s_cnt;
  int t = threadIdx.x;
  for (int j = t; j < 2048; j += 256) {
    unsigned s = 0;
#pragma unroll
    for (int r = 0; r < NREP; ++r) s += h16[r * 2048 + j];
    hsum[j] = s;
  }
  if (t == 0) { s_b = 0; s_cnt = 0; }
  __syncthreads();
  findBin(hsum, 2048, TOPK_TOTAL, 0u, sscan, &s_b, &s_cnt);
  if (t == 0) { scalU[0] = (unsigned)s_b; scalU[1] = s_cnt; }
}

// -------- fallback compact (bin >= b1), block-aggregated; guarded --------
__global__ __launch_bounds__(256) void k_compact(const float4* __restrict__ a4,
    unsigned* scalU, unsigned* __restrict__ candI, float* __restrict__ candV)
{
  if (scalU[13] == 0u) return;
  __shared__ unsigned sIdx[CSTAGE];
  __shared__ float sVal[CSTAGE];
  __shared__ unsigned sCnt, sBase;
  if (threadIdx.x == 0) sCnt = 0;
  __syncthreads();
  unsigned b1 = scalU[0];
  int stride = gridDim.x * blockDim.x;
  for (int i = blockIdx.x * 256 + threadIdx.x; i < NDI / 4; i += stride) {
    float4 f = a4[i];
    float vv[4] = {f.x, f.y, f.z, f.w};
#pragma unroll
    for (int c = 0; c < 4; ++c) {
      float v = vv[c];
      if (v > 0.f && (__float_as_uint(v) >> 21) >= b1) {
        unsigned p = atomicAdd(&sCnt, 1u);
        if (p < (unsigned)CSTAGE) { sIdx[p] = (unsigned)(i * 4 + c); sVal[p] = v; }
        else {
          unsigned g = atomicAdd(&scalU[12], 1u);
          if (g < (unsigned)CANDCAP) { candI[g] = (unsigned)(i * 4 + c); candV[g] = v; }
        }
      }
    }
  }
  __syncthreads();
  unsigned n = sCnt < (unsigned)CSTAGE ? sCnt : (unsigned)CSTAGE;
  if (threadIdx.x == 0) sBase = atomicAdd(&scalU[12], n);
  __syncthreads();
  unsigned base = sBase;
  for (unsigned j = threadIdx.x; j < n; j += 256) {
    unsigned g = base + j;
    if (g < (unsigned)CANDCAP) { candI[g] = sIdx[j]; candV[g] = sVal[j]; }
  }
}

// -------- refine level 2: multi-block histogram over candidates --------
__global__ __launch_bounds__(256) void k_rhist2(const unsigned* __restrict__ scalU,
    const float* __restrict__ candV, unsigned* __restrict__ h16)
{
  __shared__ unsigned lh[2048];
  for (int j = threadIdx.x; j < 2048; j += 256) lh[j] = 0;
  __syncthreads();
  unsigned b1 = scalU[0];
  int n = (int)scalU[12]; if (n > CANDCAP) n = CANDCAP;
  int stride = gridDim.x * blockDim.x;
  for (int j = blockIdx.x * 256 + threadIdx.x; j < n; j += stride) {
    unsigned u = __float_as_uint(candV[j]);
    if ((u >> 21) == b1) atomicAdd(&lh[(u >> 10) & 0x7FFu], 1u);
  }
  __syncthreads();
  unsigned* dst = h16 + (size_t)(blockIdx.x & (NREP - 1)) * 2048;
  for (int j = threadIdx.x; j < 2048; j += 256) {
    unsigned c = lh[j];
    if (c) atomicAdd(&dst[j], c);
  }
}

__global__ __launch_bounds__(256) void k_rscan2(unsigned* scalU, const unsigned* __restrict__ h16)
{
  __shared__ unsigned hsum[2048];
  __shared__ unsigned sscan[256];
  __shared__ int s_b; __shared__ unsigned s_cnt;
  int t = threadIdx.x;
  for (int j = t; j < 2048; j += 256) {
    unsigned s = 0;
#pragma unroll
    for (int r = 0; r < NREP; ++r) s += h16[r * 2048 + j];
    hsum[j] = s;
  }
  if (t == 0) { s_b = 0; s_cnt = 0; }
  __syncthreads();
  findBin(hsum, 2048, TOPK_TOTAL, scalU[1], sscan, &s_b, &s_cnt);
  if (t == 0) { scalU[2] = (unsigned)s_b; scalU[3] = s_cnt; }
}

// -------- refine level 3 --------
__global__ __launch_bounds__(256) void k_rhist3(const unsigned* __restrict__ scalU,
    const float* __restrict__ candV, unsigned* __restrict__ h16)
{
  __shared__ unsigned lh[1024];
  for (int j = threadIdx.x; j < 1024; j += 256) lh[j] = 0;
  __syncthreads();
  unsigned b1 = scalU[0], b2 = scalU[2];
  int n = (int)scalU[12]; if (n > CANDCAP) n = CANDCAP;
  int stride = gridDim.x * blockDim.x;
  for (int j = blockIdx.x * 256 + threadIdx.x; j < n; j += stride) {
    unsigned u = __float_as_uint(candV[j]);
    if ((u >> 21) == b1 && ((u >> 10) & 0x7FFu) == b2) atomicAdd(&lh[u & 0x3FFu], 1u);
  }
  __syncthreads();
  unsigned* dst = h16 + (size_t)(blockIdx.x & (NREP - 1)) * 1024;
  for (int j = threadIdx.x; j < 1024; j += 256) {
    unsigned c = lh[j];
    if (c) atomicAdd(&dst[j], c);
  }
}

__global__ __launch_bounds__(256) void k_rscan3(unsigned* scalU, const unsigned* __restrict__ h16)
{
  __shared__ unsigned hsum[1024];
  __shared__ unsigned sscan[256];
  __shared__ int s_b; __shared__ unsigned s_cnt;
  int t = threadIdx.x;
  for (int j = t; j < 1024; j += 256) {
    unsigned s = 0;
#pragma unroll
    for (int r = 0; r < NREP; ++r) s += h16[r * 1024 + j];
    hsum[j] = s;
  }
  if (t == 0) { s_b = 0; s_cnt = 0; }
  __syncthreads();
  findBin(hsum, 1024, TOPK_TOTAL, scalU[3], sscan, &s_b, &s_cnt);
  if (t == 0) {
    unsigned cut = (scalU[0] << 21) | (scalU[2] << 10) | (unsigned)s_b;
    scalU[4] = cut; scalU[5] = s_cnt; scalU[6] = TOPK_TOTAL - s_cnt;
  }
}

// -------- tie collection (multi-block) + resolve (tiny single-block) --------
__global__ __launch_bounds__(256) void k_tiecol(unsigned* scalU,
    const unsigned* __restrict__ candI, const float* __restrict__ candV,
    unsigned* __restrict__ tieB)
{
  unsigned cut = scalU[4];
  int n = (int)scalU[12]; if (n > CANDCAP) n = CANDCAP;
  int stride = gridDim.x * blockDim.x;
  for (int j = blockIdx.x * 256 + threadIdx.x; j < n; j += stride) {
    if (__float_as_uint(candV[j]) == cut) {
      unsigned p = atomicAdd(&scalU[14], 1u);
      if (p < (unsigned)TIECAP) tieB[p] = candI[j];
    }
  }
}

__global__ __launch_bounds__(256) void k_tieres(unsigned* scalU, const unsigned* __restrict__ tieB)
{
  __shared__ unsigned tbuf[TIECAP];
  __shared__ int sthr;
  int t = threadIdx.x;
  int m = (int)scalU[14]; if (m > TIECAP) m = TIECAP;
  int need = (int)scalU[6];
  for (int j = t; j < m; j += 256) tbuf[j] = tieB[j];
  if (t == 0) sthr = 0x7FFFFFFF;
  __syncthreads();
  if (need < m) {
    for (int ci = t; ci < m; ci += 256) {
      unsigned me = tbuf[ci];
      int r = 0;
      for (int j = 0; j < m; ++j) r += (tbuf[j] < me) ? 1 : 0;
      if (r == need - 1) sthr = (int)me;
    }
  }
  __syncthreads();
  if (t == 0) scalU[7] = (unsigned)sthr;
}

// -------- selection over candidates: per-row lists, col flags, l1/l0 --------
__global__ __launch_bounds__(256) void k_s1b(unsigned* scalU,
    const unsigned* __restrict__ candI, const float* __restrict__ candV,
    unsigned* rowCnt, unsigned* rlc, float* rlv, unsigned* colAct, double* scalD)
{
  __shared__ float redf[256];
  __shared__ unsigned redu[256];
  unsigned cut = scalU[4]; int tthr = (int)scalU[7];
  int n = (int)scalU[12]; if (n > CANDCAP) n = CANDCAP;
  float l1 = 0.f; unsigned l0 = 0;
  int stride = gridDim.x * blockDim.x;
  for (int j = blockIdx.x * 256 + threadIdx.x; j < n; j += stride) {
    float v = candV[j];
    unsigned u = __float_as_uint(v);
    unsigned idx = candI[j];
    if (u > cut || (u == cut && (int)idx <= tthr)) {
      int row = (int)(idx >> 15), col = (int)(idx & (D - 1));
      unsigned slot = atomicAdd(&rowCnt[row], 1u);
      if (slot < ROWCAP) {
        rlc[(size_t)row * ROWCAP + slot] = (unsigned)col;
        rlv[(size_t)row * ROWCAP + slot] = v;
      }
      colAct[col] = 1u;
      l1 += v; l0++;
    }
  }
  float l1s = bsumf(l1, redf);
  unsigned l0s = bsumu(l0, redu);
  if (threadIdx.x == 0) { atomicAdd(&scalD[0], (double)l1s); atomicAdd(&scalU[9], l0s); }
}

// -------- scatter selected into zeroed acts_topk --------
__global__ __launch_bounds__(256) void k_scatter(const unsigned* __restrict__ scalU,
    const unsigned* __restrict__ candI, const float* __restrict__ candV, float* __restrict__ acts)
{
  unsigned cut = scalU[4]; int tthr = (int)scalU[7];
  int n = (int)scalU[12]; if (n > CANDCAP) n = CANDCAP;
  int stride = gridDim.x * blockDim.x;
  for (int j = blockIdx.x * 256 + threadIdx.x; j < n; j += stride) {
    float v = candV[j];
    unsigned u = __float_as_uint(v);
    unsigned idx = candI[j];
    if (u > cut || (u == cut && (int)idx <= tthr)) acts[idx] = v;
  }
}

// -------- dead-column bitmask + num_dead_features --------
__global__ __launch_bounds__(256) void k_dead(const unsigned* __restrict__ colAct,
    const float* __restrict__ nbna, unsigned* deadCols, unsigned* scalU,
    u64* __restrict__ dmask, unsigned* __restrict__ dbase)
{
  __shared__ unsigned scan[256];
  __shared__ unsigned svd;
  const int t = threadIdx.x;
  if (t == 0) svd = 0;
  __syncthreads();
  const int c0 = t * 128;
  u64 w0 = 0, w1 = 0;
  unsigned vd = 0;
  for (int i = 0; i < 64; ++i) {
    int c = c0 + i;
    bool act = colAct[c] != 0;
    float f = nbna[c] + 1.0f;
    if (!act && f >= 5.0f) w0 |= (1ull << i);
    vd += (!act && f > 5.0f) ? 1u : 0u;
  }
  for (int i = 0; i < 64; ++i) {
    int c = c0 + 64 + i;
    bool act = colAct[c] != 0;
    float f = nbna[c] + 1.0f;
    if (!act && f >= 5.0f) w1 |= (1ull << i);
    vd += (!act && f > 5.0f) ? 1u : 0u;
  }
  unsigned cnt = (unsigned)(__popcll(w0) + __popcll(w1));
  scan[t] = cnt; __syncthreads();
  for (int o = 1; o < 256; o <<= 1) {
    unsigned xx = (t >= o) ? scan[t - o] : 0u; __syncthreads();
    scan[t] += xx; __syncthreads();
  }
  unsigned p = scan[t] - cnt;
  dmask[2 * t] = w0; dmask[2 * t + 1] = w1;
  dbase[2 * t] = p; dbase[2 * t + 1] = p + (unsigned)__popcll(w0);
  atomicAdd(&svd, vd);
  __syncthreads();
  if (t == 255) scalU[10] = scan[255];
  if (t == 0) scalU[11] = svd;
  (void)deadCols;
}

// -------- per-row aux top-512: 2 streaming passes + LDS boundary-bin refine --------
__global__ __launch_bounds__(256) void k_auxsel(const float* __restrict__ acts,
    const unsigned* __restrict__ scalU, const u64* __restrict__ dmask,
    unsigned* auxC, float* auxV, unsigned* auxN)
{
  __shared__ u64 smask[512];           // 4 KB
  __shared__ unsigned hist[2048];      // 8 KB
  __shared__ unsigned sscan[256];      // 1 KB
  __shared__ float tval[SCAP];         // 12 KB
  __shared__ unsigned tcol[SCAP];      // 12 KB
  __shared__ int s_b; __shared__ unsigned s_cnt;
  __shared__ unsigned s_sel, s_tm;
  const int row = blockIdx.x, t = threadIdx.x;
  const float4* arow4 = (const float4*)(acts + (size_t)row * D);

  for (int j = t; j < 512; j += 256) smask[j] = dmask[j];
  for (int j = t; j < 2048; j += 256) hist[j] = 0;
  if (t == 0) { s_sel = 0; s_tm = 0; s_b = 0; s_cnt = 0; }
  __syncthreads();

  // pass 1: positive count + level-1 (11-bit) histogram
  unsigned pcnt = 0;
  for (int j = t; j < D / 4; j += 256) {
    float4 f = arow4[j];
    u64 w = smask[j >> 4];
    int sh = (j & 15) * 4;
    float vv[4] = {f.x, f.y, f.z, f.w};
#pragma unroll
    for (int c = 0; c < 4; ++c) {
      if (((w >> (sh + c)) & 1ull) && vv[c] > 0.f) {
        pcnt++;
        atomicAdd(&hist[__float_as_uint(vv[c]) >> 21], 1u);
      }
    }
  }
  unsigned P = bsumu(pcnt, sscan);
  unsigned* outC = auxC + (size_t)row * TOPK_AUX;
  float* outV = auxV + (size_t)row * TOPK_AUX;

  if (P <= (unsigned)TOPK_AUX) {
    for (int j = t; j < D / 4; j += 256) {
      float4 f = arow4[j];
      u64 w = smask[j >> 4];
      int sh = (j & 15) * 4;
      float vv[4] = {f.x, f.y, f.z, f.w};
#pragma unroll
      for (int c = 0; c < 4; ++c)
        if (((w >> (sh + c)) & 1ull) && vv[c] > 0.f) {
          unsigned s = atomicAdd(&s_sel, 1u);
          outC[s] = (unsigned)(j * 4 + c); outV[s] = vv[c];
        }
    }
    __syncthreads();
    if (t == 0) auxN[row] = s_sel;
    return;
  }

  __syncthreads();
  findBin(hist, 2048, (unsigned)TOPK_AUX, 0u, sscan, &s_b, &s_cnt);
  unsigned b1 = (unsigned)s_b, c1 = s_cnt;

  // pass 2: bin > b1 -> emit; bin == b1 -> stage to LDS
  for (int j = t; j < D / 4; j += 256) {
    float4 f = arow4[j];
    u64 w = smask[j >> 4];
    int sh = (j & 15) * 4;
    float vv[4] = {f.x, f.y, f.z, f.w};
#pragma unroll
    for (int c = 0; c < 4; ++c) {
      if (((w >> (sh + c)) & 1ull) && vv[c] > 0.f) {
        unsigned bin = __float_as_uint(vv[c]) >> 21;
        if (bin > b1) {
          unsigned s = atomicAdd(&s_sel, 1u);
          outC[s] = (unsigned)(j * 4 + c); outV[s] = vv[c];
        } else if (bin == b1) {
          unsigned p = atomicAdd(&s_tm, 1u);
          if (p < (unsigned)SCAP) { tcol[p] = (unsigned)(j * 4 + c); tval[p] = vv[c]; }
        }
      }
    }
  }
  __syncthreads();
  int m = (int)s_tm;

  if (m <= SCAP) {
    for (int j = t; j < 2048; j += 256) hist[j] = 0;
    if (t == 0) { s_b = 0; s_cnt = 0; }
    __syncthreads();
    for (int j = t; j < m; j += 256)
      atomicAdd(&hist[(__float_as_uint(tval[j]) >> 10) & 0x7FFu], 1u);
    __syncthreads();
    findBin(hist, 2048, (unsigned)TOPK_AUX, c1, sscan, &s_b, &s_cnt);
    unsigned b2 = (unsigned)s_b, c2 = s_cnt;
    for (int j = t; j < 1024; j += 256) hist[j] = 0;
    if (t == 0) { s_b = 0; s_cnt = 0; }
    __syncthreads();
    for (int j = t; j < m; j += 256) {
      unsigned u = __float_as_uint(tval[j]);
      if (((u >> 10) & 0x7FFu) == b2) atomicAdd(&hist[u & 0x3FFu], 1u);
    }
    __syncthreads();
    findBin(hist, 1024, (unsigned)TOPK_AUX, c2, sscan, &s_b, &s_cnt);
    unsigned cut = (b1 << 21) | (b2 << 10) | (unsigned)s_b;
    int need = TOPK_AUX - (int)s_cnt;
    for (int j = t; j < m; j += 256) {
      unsigned u = __float_as_uint(tval[j]);
      if (u > cut) {
        unsigned s = atomicAdd(&s_sel, 1u);
        outC[s] = tcol[j]; outV[s] = tval[j];
      } else if (u == cut) {
        unsigned col = tcol[j];
        int r = 0;
        for (int k = 0; k < m; ++k)
          r += (__float_as_uint(tval[k]) == cut && tcol[k] < col) ? 1 : 0;
        if (r < need) { unsigned s = atomicAdd(&s_sel, 1u); outC[s] = col; outV[s] = tval[j]; }
      }
    }
    __syncthreads();
    if (t == 0) auxN[row] = s_sel;
    return;
  }

  // ---- fallback (staged overflow): global streaming refine, exact ----
  for (int j = t; j < 2048; j += 256) hist[j] = 0;
  if (t == 0) { s_b = 0; s_cnt = 0; }
  __syncthreads();
  for (int j = t; j < D / 4; j += 256) {
    float4 f = arow4[j];
    u64 w = smask[j >> 4];
    int sh = (j & 15) * 4;
    float vv[4] = {f.x, f.y, f.z, f.w};
#pragma unroll
    for (int c = 0; c < 4; ++c) {
      if (((w >> (sh + c)) & 1ull) && vv[c] > 0.f) {
        unsigned u = __float_as_uint(vv[c]);
        if ((u >> 21) == b1) atomicAdd(&hist[(u >> 10) & 0x7FFu], 1u);
      }
    }
  }
  __syncthreads();
  findBin(hist, 2048, (unsigned)TOPK_AUX, c1, sscan, &s_b, &s_cnt);
  unsigned b2 = (unsigned)s_b, c2 = s_cnt;
  for (int j = t; j < 1024; j += 256) hist[j] = 0;
  if (t == 0) { s_b = 0; s_cnt = 0; }
  __syncthreads();
  unsigned hi21 = (b1 << 11) | b2;
  for (int j = t; j < D / 4; j += 256) {
    float4 f = arow4[j];
    u64 w = smask[j >> 4];
    int sh = (j & 15) * 4;
    float vv[4] = {f.x, f.y, f.z, f.w};
#pragma unroll
    for (int c = 0; c < 4; ++c) {
      if (((w >> (sh + c)) & 1ull) && vv[c] > 0.f) {
        unsigned u = __float_as_uint(vv[c]);
        if ((u >> 10) == hi21) atomicAdd(&hist[u & 0x3FFu], 1u);
      }
    }
  }
  __syncthreads();
  findBin(hist, 1024, (unsigned)TOPK_AUX, c2, sscan, &s_b, &s_cnt);
  unsigned cut = (b1 << 21) | (b2 << 10) | (unsigned)s_b;
  int need = TOPK_AUX - (int)s_cnt;
  if (t == 0) s_tm = 0;
  __syncthreads();
  for (int j = t; j < D / 4; j += 256) {
    float4 f = arow4[j];
    u64 w = smask[j >> 4];
    int sh = (j & 15) * 4;
    float vv[4] = {f.x, f.y, f.z, f.w};
#pragma unroll
    for (int c = 0; c < 4; ++c) {
      if (((w >> (sh + c)) & 1ull) && vv[c] > 0.f) {
        unsigned u = __float_as_uint(vv[c]);
        if (u > cut && (u >> 21) == b1) {
          unsigned s = atomicAdd(&s_sel, 1u);
          outC[s] = (unsigned)(j * 4 + c); outV[s] = vv[c];
        } else if (u == cut) {
          unsigned p = atomicAdd(&s_tm, 1u);
          if (p < (unsigned)SCAP) tcol[p] = (unsigned)(j * 4 + c);
        }
      }
    }
  }
  __syncthreads();
  int mm = (int)s_tm; if (mm > SCAP) mm = SCAP;
  float cv = __uint_as_float(cut);
  for (int ci = t; ci < mm; ci += 256) {
    unsigned col = tcol[ci];
    int r = 0;
    for (int j = 0; j < mm; ++j) r += (tcol[j] < col) ? 1 : 0;
    if (r < need) { unsigned s = atomicAdd(&s_sel, 1u); outC[s] = col; outV[s] = cv; }
  }
  __syncthreads();
  if (t == 0) auxN[row] = s_sel;
}

// -------- sparse matryoshka decode (bf16 Wdec) + per-group MSE + sae_out + residual --------
__global__ __launch_bounds__(256) void k_decode(const u16* __restrict__ Wdecb,
    const float* __restrict__ bdec, const float* __restrict__ xn,
    const unsigned* __restrict__ rowCnt, const unsigned* __restrict__ rlc,
    const float* __restrict__ rlv, const float* __restrict__ rmean,
    const float* __restrict__ rstd, float* __restrict__ sae,
    float* __restrict__ resid, double* scalD)
{
  __shared__ int tlc[ROWCAP]; __shared__ float tlv[ROWCAP];
  __shared__ int slc[ROWCAP]; __shared__ float slv[ROWCAP];
  __shared__ int gcnt[5], gpos[5], gend[5];
  __shared__ float red[256];
  const int row = blockIdx.x, t = threadIdx.x;
  int cnt = (int)rowCnt[row]; if (cnt > ROWCAP) cnt = ROWCAP;
  if (t < 5) gcnt[t] = 0;
  __syncthreads();
  for (int e = t; e < cnt; e += 256) {
    int c = (int)rlc[(size_t)row * ROWCAP + e];
    tlc[e] = c; tlv[e] = rlv[(size_t)row * ROWCAP + e];
    int ilog = 31 - __clz(c | 1);
    int g = ilog > 10 ? ilog - 10 : 0;
    atomicAdd(&gcnt[g], 1);
  }
  __syncthreads();
  if (t == 0) {
    int b = 0;
    for (int g = 0; g < 5; ++g) { gpos[g] = b; b += gcnt[g]; gend[g] = b; }
  }
  __syncthreads();
  for (int e = t; e < cnt; e += 256) {
    int c = tlc[e];
    int ilog = 31 - __clz(c | 1);
    int g = ilog > 10 ? ilog - 10 : 0;
    int p = atomicAdd(&gpos[g], 1);
    slc[p] = c; slv[p] = tlv[e];
  }
  __syncthreads();
  float r0 = bdec[t], r1 = bdec[t + 256], r2 = bdec[t + 512];
  size_t o = (size_t)row * DIN;
  float x0 = xn[o + t], x1 = xn[o + t + 256], x2 = xn[o + t + 512];
  int e = 0;
#pragma unroll 1
  for (int g = 0; g < 5; ++g) {
    int e1 = gend[g];
#pragma unroll 2
    for (; e < e1; ++e) {
      int c = slc[e]; float v = slv[e];
      const u16* w = Wdecb + (size_t)c * DIN;
      r0 = fmaf(v, b2f(w[t]), r0);
      r1 = fmaf(v, b2f(w[t + 256]), r1);
      r2 = fmaf(v, b2f(w[t + 512]), r2);
    }
    float dd0 = r0 - x0, dd1 = r1 - x1, dd2 = r2 - x2;
    float sq = bsumf(dd0 * dd0 + dd1 * dd1 + dd2 * dd2, red);
    if (t == 0) atomicAdd(&scalD[4 + g], (double)sq);
  }
  float m = rmean[row], sd = rstd[row];
  sae[o + t] = r0 * sd + m; sae[o + t + 256] = r1 * sd + m; sae[o + t + 512] = r2 * sd + m;
  resid[o + t] = x0 - r0; resid[o + t + 256] = x1 - r1; resid[o + t + 512] = x2 - r2;
}

// -------- aux decode (bf16 Wdec) + aux MSE --------
__global__ __launch_bounds__(256) void k_auxdec(const u16* __restrict__ Wdecb,
    const unsigned* __restrict__ auxC, const float* __restrict__ auxV,
    const unsigned* __restrict__ auxN, const float* __restrict__ resid, double* scalD)
{
  __shared__ int lc[TOPK_AUX]; __shared__ float lv[TOPK_AUX];
  __shared__ float red[256];
  const int row = blockIdx.x, t = threadIdx.x;
  int cnt = (int)auxN[row]; if (cnt > TOPK_AUX) cnt = TOPK_AUX;
  for (int e = t; e < cnt; e += 256) {
    lc[e] = (int)auxC[(size_t)row * TOPK_AUX + e];
    lv[e] = auxV[(size_t)row * TOPK_AUX + e];
  }
  __syncthreads();
  float a0 = 0.f, a1 = 0.f, a2 = 0.f;
#pragma unroll 4
  for (int e = 0; e < cnt; ++e) {
    int c = lc[e]; float v = lv[e];
    const u16* w = Wdecb + (size_t)c * DIN;
    a0 = fmaf(v, b2f(w[t]), a0);
    a1 = fmaf(v, b2f(w[t + 256]), a1);
    a2 = fmaf(v, b2f(w[t + 512]), a2);
  }
  size_t o = (size_t)row * DIN;
  float s0 = resid[o + t], s1 = resid[o + t + 256], s2 = resid[o + t + 512];
  float d0 = a0 - s0, d1 = a1 - s1, d2 = a2 - s2;
  float sq = bsumf(d0 * d0 + d1 * d1 + d2 * d2, red);
  float ab = bsumf(fabsf(a0) + fabsf(a1) + fabsf(a2), red);
  if (t == 0) { atomicAdd(&scalD[9], (double)sq); atomicAdd(&scalD[10], (double)ab); }
}

// -------- scalar finalize --------
__global__ void k_final(const unsigned* __restrict__ scalU, const double* __restrict__ scalD,
                        const float* __restrict__ thr, float* __restrict__ out)
{
  if (threadIdx.x != 0 || blockIdx.x != 0) return;
  const double NEL = (double)B * (double)DIN;
  double term0 = scalD[3] / NEL;
  double tot = term0;
  double mn = 1e300, mx = -1e300;
  for (int g = 0; g < 5; ++g) {
    double l2 = scalD[4 + g] / NEL;
    tot += l2;
    mn = l2 < mn ? l2 : mn;
    mx = l2 > mx ? l2 : mx;
  }
  double mean_l2 = tot / 6.0;
  double sum = scalD[1], ssq = scalD[2];
  double xvar = (ssq - sum * sum / NEL) / (NEL - 1.0);
  double fvu = mean_l2 / (xvar + 1e-10);
  double l1n = scalD[0] / (double)B;
  double l1loss = (double)0.0003f * l1n;
  double l0n = (double)scalU[9] / (double)B;
  double auxmse = scalD[9] / NEL;
  double auxloss = (scalD[10] > 0.0) ? 0.03125 * auxmse : 0.0;
  double loss = mean_l2 + l1loss + auxloss;
  float cutv = __uint_as_float(scalU[4]);
  float t0 = thr[0];
  float newthr = (scalU[9] > 0u) ? (0.99f * t0 + 0.01f * cutv) : t0;
  float* s = out + (size_t)B * DIN + (size_t)NDI;
  s[0] = (float)loss;   s[1] = (float)l1loss; s[2] = (float)mean_l2;
  s[3] = (float)mn;     s[4] = (float)mx;     s[5] = (float)l0n;
  s[6] = (float)l1n;    s[7] = (float)auxloss; s[8] = newthr;
  s[9] = (float)fvu;    s[10] = (float)scalU[11];
}

extern "C" void kernel_launch(void* const* d_in, const int* in_sizes, int n_in,
                              void* d_out, int out_size, void* d_ws, size_t ws_size,
                              hipStream_t stream)
{
  (void)in_sizes; (void)n_in; (void)out_size; (void)ws_size;
  const float* x    = (const float*)d_in[0];
  const float* Wenc = (const float*)d_in[1];
  const float* Wdec = (const float*)d_in[2];
  const float* bdec = (const float*)d_in[3];
  const float* nbna = (const float*)d_in[4];
  const float* thr  = (const float*)d_in[5];
  float* out = (float*)d_out;
  char* ws = (char*)d_ws;

  float* sae  = out;
  float* acts = out + (size_t)B * DIN;   // acts / acts_topk live in the output region

  unsigned* hist1 = (unsigned*)(ws + OFF_HIST1);
  unsigned* hist2 = (unsigned*)(ws + OFF_HIST2);
  unsigned* hist3 = (unsigned*)(ws + OFF_HIST3);
  unsigned* hist4 = (unsigned*)(ws + OFF_HIST4);
  unsigned* scalU = (unsigned*)(ws + OFF_SCALU);
  double*   scalD = (double*)(ws + OFF_SCALD);
  unsigned* rowCnt= (unsigned*)(ws + OFF_ROWCNT);
  unsigned* auxN  = (unsigned*)(ws + OFF_AUXCNT);
  unsigned* colAct= (unsigned*)(ws + OFF_COLACT);
  float* xn    = (float*)(ws + OFF_XN);
  float* resid = (float*)(ws + OFF_RES);
  float* rmean = (float*)(ws + OFF_RMEAN);
  float* rstd  = (float*)(ws + OFF_RSTD);
  u16*   xncb  = (u16*)(ws + OFF_XNCB);
  unsigned* deadC = (unsigned*)(ws + OFF_DEAD);
  u64*      dmask = (u64*)(ws + OFF_DMASK);
  unsigned* dbase = (unsigned*)(ws + OFF_DBASE);
  unsigned* rlc = (unsigned*)(ws + OFF_RLC);
  float*    rlv = (float*)(ws + OFF_RLV);
  unsigned* auxC = (unsigned*)(ws + OFF_AXC);
  float*    auxV = (float*)(ws + OFF_AXV);
  unsigned* candI = (unsigned*)(ws + OFF_CANDI);
  float*    candV = (float*)(ws + OFF_CANDV);
  unsigned* tieB  = (unsigned*)(ws + OFF_TIEB);
  u16* Wt    = (u16*)(ws + OFF_WT);   // WencT bf16, later reused as Wdec bf16
  u16* Wdecb = (u16*)(ws + OFF_WT);

  hipMemsetAsync(ws, 0, ZERO_BYTES, stream);
  hipLaunchKernelGGL(k_rowstats, dim3(B), dim3(256), 0, stream, x, bdec, xn, xncb, rmean, rstd, scalD);
  hipLaunchKernelGGL(k_wt, dim3(D / 64, DIN / 64), dim3(256), 0, stream, Wenc, Wt);
  hipLaunchKernelGGL(k_gemm, dim3(B / 128, D / 128), dim3(256), 0, stream, xncb, Wt, acts, hist1, scalU, candI, candV);
  hipLaunchKernelGGL(k_scan1a, dim3(1), dim3(256), 0, stream, scalU, hist1);
  hipLaunchKernelGGL(k_histfull, dim3(2048), dim3(256), 0, stream, (const float4*)acts, scalU, hist2);
  hipLaunchKernelGGL(k_scan1b, dim3(1), dim3(256), 0, stream, scalU, hist2);
  hipLaunchKernelGGL(k_compact, dim3(2048), dim3(256), 0, stream, (const float4*)acts, scalU, candI, candV);
  hipLaunchKernelGGL(k_wdecb, dim3(2048), dim3(256), 0, stream, (const float4*)Wdec, Wdecb);
  hipLaunchKernelGGL(k_rhist2, dim3(256), dim3(256), 0, stream, scalU, candV, hist3);
  hipLaunchKernelGGL(k_rscan2, dim3(1), dim3(256), 0, stream, scalU, hist3);
  hipLaunchKernelGGL(k_rhist3, dim3(256), dim3(256), 0, stream, scalU, candV, hist4);
  hipLaunchKernelGGL(k_rscan3, dim3(1), dim3(256), 0, stream, scalU, hist4);
  hipLaunchKernelGGL(k_tiecol, dim3(256), dim3(256), 0, stream, scalU, candI, candV, tieB);
  hipLaunchKernelGGL(k_tieres, dim3(1), dim3(256), 0, stream, scalU, tieB);
  hipLaunchKernelGGL(k_s1b, dim3(256), dim3(256), 0, stream, scalU, candI, candV, rowCnt, rlc, rlv, colAct, scalD);
  hipLaunchKernelGGL(k_dead, dim3(1), dim3(256), 0, stream, colAct, nbna, deadC, scalU, dmask, dbase);
  hipLaunchKernelGGL(k_auxsel, dim3(B), dim3(256), 0, stream, acts, scalU, dmask, auxC, auxV, auxN);
  hipMemsetAsync(acts, 0, (size_t)NDI * 4, stream);
  hipLaunchKernelGGL(k_scatter, dim3(256), dim3(256), 0, stream, scalU, candI, candV, acts);
  hipLaunchKernelGGL(k_decode, dim3(B), dim3(256), 0, stream, Wdecb, bdec, xn, rowCnt, rlc, rlv, rmean, rstd, sae, resid, scalD);
  hipLaunchKernelGGL(k_auxdec, dim3(B), dim3(256), 0, stream, Wdecb, auxC, auxV, auxN, resid, scalD);
  hipLaunchKernelGGL(k_final, dim3(1), dim3(64), 0, stream, scalU, scalD, thr, out);
}

// Round 10
// 968.116 us; speedup vs baseline: 1.0099x; 1.0099x over previous
//
#include <hip/hip_runtime.h>
#include <stdint.h>

#define DEVFN static __device__ __forceinline__

typedef unsigned short u16;
typedef unsigned long long u64;
typedef short short8 __attribute__((ext_vector_type(8)));
typedef float vf4 __attribute__((ext_vector_type(4)));

constexpr int B = 2048;
constexpr int DIN = 768;
constexpr int D = 32768;
constexpr int NDI = B * D;                 // 67,108,864
constexpr unsigned TOPK_TOTAL = 65536u;    // 32 * B
constexpr int TOPK_AUX = 512;
constexpr int ROWCAP = 512;
constexpr int CANDCAP = 3145728;           // candidates with v>=1.0 (~2.38M measured-model)
constexpr int GSTAGE = 2048;               // per-GEMM-block LDS cand stage
constexpr int CSTAGE = 4096;
constexpr int TIECAP = 4096;
constexpr int SCAP = 3072;                 // aux boundary-bin LDS stage cap
constexpr int NREP = 16;                   // global histogram replicas

// ---------------- workspace layout (bytes) ----------------
constexpr size_t OFF_HIST1  = 0;                          // 16 x 8192 (level-1, from GEMM)
constexpr size_t OFF_HIST2  = 131072;                     // 16 x 8192 (fallback full hist)
constexpr size_t OFF_HIST3  = 262144;                     // 16 x 8192 (refine level-2)
constexpr size_t OFF_HIST4  = 393216;                     // 16 x 4096 (refine level-3)
constexpr size_t OFF_SCALU  = 458752;                     // u32[64]
constexpr size_t OFF_SCALD  = 459008;                     // double[32]
constexpr size_t OFF_ROWCNT = 459264;                     // 8192
constexpr size_t OFF_AUXCNT = 467456;                     // 8192
constexpr size_t OFF_COLACT = 475648;                     // 131072
constexpr size_t ZERO_BYTES = 606720;
constexpr size_t OFF_XN    = ZERO_BYTES;                  // 6291456
constexpr size_t OFF_RES   = OFF_XN   + 6291456;          // 6291456
constexpr size_t OFF_RMEAN = OFF_RES  + 6291456;          // 8192
constexpr size_t OFF_RSTD  = OFF_RMEAN + 8192;            // 8192
constexpr size_t OFF_XNCB  = OFF_RSTD + 8192;             // 3145728 (bf16 xnc)
constexpr size_t OFF_DEAD  = OFF_XNCB + 3145728;          // 131072
constexpr size_t OFF_DMASK = OFF_DEAD + 131072;           // 4096  (512 x u64 dead bitmask)
constexpr size_t OFF_DBASE = OFF_DMASK + 4096;            // 2048  (512 x u32 prefix base)
constexpr size_t OFF_RLC   = OFF_DBASE + 2048;            // 4194304
constexpr size_t OFF_RLV   = OFF_RLC  + 4194304;          // 4194304
constexpr size_t OFF_AXC   = OFF_RLV  + 4194304;          // 4194304
constexpr size_t OFF_AXV   = OFF_AXC  + 4194304;          // 4194304
constexpr size_t OFF_CANDI = OFF_AXV  + 4194304;          // 12582912
constexpr size_t OFF_CANDV = OFF_CANDI + (size_t)CANDCAP * 4; // 12582912
constexpr size_t OFF_TIEB  = OFF_CANDV + (size_t)CANDCAP * 4; // 16384
constexpr size_t OFF_WT    = OFF_TIEB + (size_t)TIECAP * 4;   // 50331648 (WencT bf16; reused as Wdec bf16)

// scalU: 0 b1, 1 cntgt1, 2 b2, 3 cntgt2, 4 cutoff_bits, 5 cntgt_final, 6 need,
//        7 tie_thr(i32), 9 l0_count, 10 n_dead, 11 num_dead_feat, 12 cand_count,
//        13 needFull, 14 tie_count
// scalD: 0 l1_sum, 1 sum_xn, 2 sumsq_xn, 3 sq0, 4..8 group_sq[5], 9 aux_sq, 10 aux_abs

DEVFN u16 f2bf(float f) {
  unsigned u = __float_as_uint(f);
  unsigned r = (u + 0x7FFFu + ((u >> 16) & 1u)) >> 16;
  return (u16)r;
}
DEVFN float b2f(u16 h) { return __uint_as_float(((unsigned)h) << 16); }

DEVFN float bsumf(float v, float* red) {
  int t = threadIdx.x;
  red[t] = v; __syncthreads();
  for (int o = 128; o > 0; o >>= 1) { if (t < o) red[t] += red[t + o]; __syncthreads(); }
  float r = red[0]; __syncthreads();
  return r;
}
DEVFN unsigned bsumu(unsigned v, unsigned* red) {
  int t = threadIdx.x;
  red[t] = v; __syncthreads();
  for (int o = 128; o > 0; o >>= 1) { if (t < o) red[t] += red[t + o]; __syncthreads(); }
  unsigned r = red[0]; __syncthreads();
  return r;
}

// Find bin (scanning from the top) where cumulative count reaches K.
DEVFN void findBin(const unsigned* hist, int nb, unsigned K, unsigned base,
                   unsigned* sscan, int* s_b, unsigned* s_cnt)
{
  int t = threadIdx.x;
  int chunk = nb >> 8;
  int hi = nb - 1 - t * chunk;
  unsigned p = 0;
  for (int k = 0; k < chunk; ++k) p += hist[hi - k];
  sscan[t] = p; __syncthreads();
  for (int o = 1; o < 256; o <<= 1) {
    unsigned xx = (t >= o) ? sscan[t - o] : 0u; __syncthreads();
    sscan[t] += xx; __syncthreads();
  }
  unsigned incl = sscan[t], excl = incl - p;
  unsigned cum = base + excl;
  if (base + incl >= K && cum < K) {
    unsigned acc = cum;
    for (int k = 0; k < chunk; ++k) {
      unsigned h = hist[hi - k];
      if (acc + h >= K) { *s_b = hi - k; *s_cnt = acc; break; }
      acc += h;
    }
  }
  __syncthreads();
}

// -------- row stats + normalization (+ bf16 xnc) --------
__global__ __launch_bounds__(256) void k_rowstats(
    const float* __restrict__ x, const float* __restrict__ bdec,
    float* __restrict__ xn, u16* __restrict__ xncb,
    float* __restrict__ rmean, float* __restrict__ rstd, double* scalD)
{
  __shared__ float red[256];
  const int row = blockIdx.x, t = threadIdx.x;
  const float* xr = x + (size_t)row * DIN;
  float v0 = xr[t], v1 = xr[t + 256], v2 = xr[t + 512];
  float mean = bsumf(v0 + v1 + v2, red) * (1.0f / DIN);
  float d0 = v0 - mean, d1 = v1 - mean, d2 = v2 - mean;
  float var = bsumf(d0 * d0 + d1 * d1 + d2 * d2, red) * (1.0f / (DIN - 1));
  float sd = sqrtf(var);
  float inv = 1.0f / (sd + 1e-5f);
  float n0 = d0 * inv, n1 = d1 * inv, n2 = d2 * inv;
  size_t o = (size_t)row * DIN;
  xn[o + t] = n0; xn[o + t + 256] = n1; xn[o + t + 512] = n2;
  float b0 = bdec[t], b1 = bdec[t + 256], b2 = bdec[t + 512];
  xncb[o + t] = f2bf(n0 - b0); xncb[o + t + 256] = f2bf(n1 - b1); xncb[o + t + 512] = f2bf(n2 - b2);
  if (t == 0) { rmean[row] = mean; rstd[row] = sd; }
  float sxn = bsumf(n0 + n1 + n2, red);
  float ssq = bsumf(n0 * n0 + n1 * n1 + n2 * n2, red);
  float e0 = b0 - n0, e1 = b1 - n1, e2 = b2 - n2;
  float sq0 = bsumf(e0 * e0 + e1 * e1 + e2 * e2, red);
  if (t == 0) {
    atomicAdd(&scalD[1], (double)sxn);
    atomicAdd(&scalD[2], (double)ssq);
    atomicAdd(&scalD[3], (double)sq0);
  }
}

// -------- W_enc [768][32768] f32 -> Wt [32768][768] bf16 (transpose+convert) --------
__global__ __launch_bounds__(256) void k_wt(const float* __restrict__ W, u16* __restrict__ Wt)
{
  __shared__ float tl[64][65];
  const int t = threadIdx.x;
  const int n0 = blockIdx.x * 64, k0 = blockIdx.y * 64;
  const int rr = t >> 6, cc = t & 63;
#pragma unroll
  for (int r = 0; r < 16; ++r) {
    int kk = r * 4 + rr;
    tl[kk][cc] = W[(size_t)(k0 + kk) * D + n0 + cc];
  }
  __syncthreads();
#pragma unroll
  for (int r = 0; r < 16; ++r) {
    int nn = r * 4 + rr;
    Wt[(size_t)(n0 + nn) * DIN + k0 + cc] = f2bf(tl[cc][nn]);
  }
}

// -------- W_dec [32768][768] f32 -> bf16 (elementwise) --------
__global__ __launch_bounds__(256) void k_wdecb(const float4* __restrict__ W4, u16* __restrict__ Wb)
{
  int stride = gridDim.x * blockDim.x;
  const int n4 = (D * DIN) / 4;
  for (int i = blockIdx.x * 256 + threadIdx.x; i < n4; i += stride) {
    float4 f = W4[i];
    unsigned p0 = (unsigned)f2bf(f.x) | ((unsigned)f2bf(f.y) << 16);
    unsigned p1 = (unsigned)f2bf(f.z) | ((unsigned)f2bf(f.w) << 16);
    uint2 q; q.x = p0; q.y = p1;
    *(uint2*)&Wb[(size_t)i * 4] = q;
  }
}

// -------- encode GEMM: acts(bf16) = relu(xnc @ Wenc) + hist + ballot-compacted cands --------
// Grid: (D/128, B/128) — bn on x (measured-best r8 orientation).
__global__ __launch_bounds__(256) void k_gemm(const u16* __restrict__ A,
                                              const u16* __restrict__ Bt,
                                              u16* __restrict__ Cb,
                                              unsigned* __restrict__ hist16,
                                              unsigned* __restrict__ scalU,
                                              unsigned* __restrict__ candI,
                                              float* __restrict__ candV)
{
  __shared__ __align__(16) char lds[32768];
  __shared__ unsigned sCnt, sBase;
  const int tid = threadIdx.x, lane = tid & 63, wid = tid >> 6;
  const int bn = blockIdx.x * 128, bm = blockIdx.y * 128;

  const char* pA[4]; const char* pB[4];
#pragma unroll
  for (int i = 0; i < 4; ++i) {
    int G = i * 256 + wid * 64 + lane;
    int r = G >> 3, c = (G & 7) ^ (r & 7);
    pA[i] = (const char*)(A + (size_t)(bm + r) * DIN + c * 8);
    pB[i] = (const char*)(Bt + (size_t)(bn + r) * DIN + c * 8);
  }
  int aoff[2][4], boff[2][4];
#pragma unroll
  for (int kc = 0; kc < 2; ++kc)
#pragma unroll
    for (int i = 0; i < 4; ++i) {
      int cs = kc * 4 + (lane >> 4);
      int rA = (wid >> 1) * 64 + i * 16 + (lane & 15);
      aoff[kc][i] = rA * 128 + ((cs ^ (rA & 7)) * 16);
      int rB = (wid & 1) * 64 + i * 16 + (lane & 15);
      boff[kc][i] = 16384 + rB * 128 + ((cs ^ (rB & 7)) * 16);
    }

  vf4 acc[4][4];
#pragma unroll
  for (int i = 0; i < 4; ++i)
#pragma unroll
    for (int j = 0; j < 4; ++j) acc[i][j] = (vf4)0.f;

  for (int ks = 0; ks < 12; ++ks) {
    __syncthreads();
#pragma unroll
    for (int i = 0; i < 4; ++i) {
      __builtin_amdgcn_global_load_lds(
          (const __attribute__((address_space(1))) void*)pA[i],
          (__attribute__((address_space(3))) void*)(lds + (i * 256 + wid * 64) * 16), 16, 0, 0);
      __builtin_amdgcn_global_load_lds(
          (const __attribute__((address_space(1))) void*)pB[i],
          (__attribute__((address_space(3))) void*)(lds + 16384 + (i * 256 + wid * 64) * 16), 16, 0, 0);
      pA[i] += 128; pB[i] += 128;
    }
    __syncthreads();
#pragma unroll
    for (int kc = 0; kc < 2; ++kc) {
      short8 av[4], bv[4];
#pragma unroll
      for (int i = 0; i < 4; ++i) {
        av[i] = *(const short8*)(lds + aoff[kc][i]);
        bv[i] = *(const short8*)(lds + boff[kc][i]);
      }
#pragma unroll
      for (int i = 0; i < 4; ++i)
#pragma unroll
        for (int j = 0; j < 4; ++j)
          acc[i][j] = __builtin_amdgcn_mfma_f32_16x16x32_bf16(av[i], bv[j], acc[i][j], 0, 0, 0);
    }
  }

  // epilogue: LDS reused as hist (8KB) + candidate stage (16KB)
  unsigned* h = (unsigned*)lds;
  unsigned* stIdx = (unsigned*)(lds + 8192);
  float* stVal = (float*)(lds + 16384);
  __syncthreads();
  for (int j = tid; j < 2048; j += 256) h[j] = 0;
  if (tid == 0) sCnt = 0;
  __syncthreads();

  const int r0 = bm + (wid >> 1) * 64 + (lane >> 4) * 4;
  const int c0 = bn + (wid & 1) * 64 + (lane & 15);
#pragma unroll
  for (int i = 0; i < 4; ++i)
#pragma unroll
    for (int j = 0; j < 4; ++j) {
      u16* cp = Cb + (size_t)(r0 + i * 16) * D + c0 + j * 16;
#pragma unroll
      for (int q = 0; q < 4; ++q) {
        float v = fmaxf(acc[i][j][q], 0.f);
        cp[(size_t)q * D] = f2bf(v);
        bool sel = (v >= 1.0f);
        u64 m = __ballot(sel);
        if (m) {
          if (sel) atomicAdd(&h[__float_as_uint(v) >> 21], 1u);
          unsigned cnt = (unsigned)__popcll(m);
          int leader = (int)__builtin_ctzll(m);
          unsigned base = 0;
          if (lane == leader) base = atomicAdd(&sCnt, cnt);
          base = __shfl(base, leader, 64);
          if (sel) {
            unsigned p = base + (unsigned)__popcll(m & ((1ull << lane) - 1ull));
            unsigned idx = ((unsigned)(r0 + i * 16 + q) << 15) | (unsigned)(c0 + j * 16);
            if (p < (unsigned)GSTAGE) { stIdx[p] = idx; stVal[p] = v; }
            else {
              unsigned g = atomicAdd(&scalU[12], 1u);
              if (g < (unsigned)CANDCAP) { candI[g] = idx; candV[g] = v; }
            }
          }
        }
      }
    }
  __syncthreads();
  unsigned* dst = hist16 + (size_t)(blockIdx.x & (NREP - 1)) * 2048;
  for (int j = 508 + tid; j < 2048; j += 256) {
    unsigned c = h[j];
    if (c) atomicAdd(&dst[j], c);
  }
  unsigned n = sCnt < (unsigned)GSTAGE ? sCnt : (unsigned)GSTAGE;
  if (tid == 0) sBase = atomicAdd(&scalU[12], n);
  __syncthreads();
  unsigned base = sBase;
  for (unsigned jj = tid; jj < n; jj += 256) {
    unsigned g = base + jj;
    if (g < (unsigned)CANDCAP) { candI[g] = stIdx[jj]; candV[g] = stVal[jj]; }
  }
}

// -------- scan over thresholded histogram; detect fallback need --------
__global__ __launch_bounds__(256) void k_scan1a(unsigned* scalU, const unsigned* __restrict__ h16)
{
  __shared__ unsigned hsum[2048];
  __shared__ unsigned sscan[256];
  __shared__ int s_b; __shared__ unsigned s_cnt;
  int t = threadIdx.x;
  for (int j = t; j < 2048; j += 256) {
    unsigned s = 0;
#pragma unroll
    for (int r = 0; r < NREP; ++r) s += h16[r * 2048 + j];
    hsum[j] = s;
  }
  if (t == 0) { s_b = 0; s_cnt = 0; }
  __syncthreads();
  unsigned p = 0;
  for (int j = 508 + t; j < 2048; j += 256) p += hsum[j];
  unsigned total = bsumu(p, sscan);
  if (total >= TOPK_TOTAL) {
    findBin(hsum, 2048, TOPK_TOTAL, 0u, sscan, &s_b, &s_cnt);
    if (t == 0) { scalU[0] = (unsigned)s_b; scalU[1] = s_cnt; scalU[13] = 0u; }
  } else if (t == 0) { scalU[13] = 1u; scalU[12] = 0u; }  // rebuild cand list in fallback
}

// -------- fallback: full positive histogram over bf16 acts (normally immediate-return) --------
__global__ __launch_bounds__(256) void k_histfull(const uint4* __restrict__ a8,
    const unsigned* __restrict__ scalU, unsigned* __restrict__ h16)
{
  if (scalU[13] == 0u) return;
  __shared__ unsigned lh[4][2048];
  for (int j = threadIdx.x; j < 8192; j += 256) ((unsigned*)lh)[j] = 0;
  __syncthreads();
  unsigned* mylh = lh[threadIdx.x & 3];
  int stride = gridDim.x * blockDim.x;
  for (int i = blockIdx.x * 256 + threadIdx.x; i < NDI / 8; i += stride) {
    uint4 f = a8[i];
    unsigned uu[4] = {f.x, f.y, f.z, f.w};
#pragma unroll
    for (int c = 0; c < 8; ++c) {
      unsigned hb = (uu[c >> 1] >> ((c & 1) * 16)) & 0xFFFFu;
      if (hb && !(hb & 0x8000u)) atomicAdd(&mylh[hb >> 5], 1u);
    }
  }
  __syncthreads();
  unsigned* dst = h16 + (size_t)(blockIdx.x & (NREP - 1)) * 2048;
  for (int j = threadIdx.x; j < 2048; j += 256) {
    unsigned c = lh[0][j] + lh[1][j] + lh[2][j] + lh[3][j];
    if (c) atomicAdd(&dst[j], c);
  }
}

__global__ __launch_bounds__(256) void k_scan1b(unsigned* scalU, const unsigned* __restrict__ h16)
{
  if (scalU[13] == 0u) return;
  __shared__ unsigned hsum[2048];
  __shared__ unsigned sscan[256];
  __shared__ int s_b; __shared__ unsigned s_cnt;
  int t = threadIdx.x;
  for (int j = t; j < 2048; j += 256) {
    unsigned s = 0;
#pragma unroll
    for (int r = 0; r < NREP; ++r) s += h16[r * 2048 + j];
    hsum[j] = s;
  }
  if (t == 0) { s_b = 0; s_cnt = 0; }
  __syncthreads();
  findBin(hsum, 2048, TOPK_TOTAL, 0u, sscan, &s_b, &s_cnt);
  if (t == 0) { scalU[0] = (unsigned)s_b; scalU[1] = s_cnt; }
}

// -------- fallback compact (bin >= b1) over bf16 acts; guarded --------
__global__ __launch_bounds__(256) void k_compact(const uint4* __restrict__ a8,
    unsigned* scalU, unsigned* __restrict__ candI, float* __restrict__ candV)
{
  if (scalU[13] == 0u) return;
  __shared__ unsigned sIdx[CSTAGE];
  __shared__ float sVal[CSTAGE];
  __shared__ unsigned sCnt, sBase;
  if (threadIdx.x == 0) sCnt = 0;
  __syncthreads();
  unsigned b1 = scalU[0];
  int stride = gridDim.x * blockDim.x;
  for (int i = blockIdx.x * 256 + threadIdx.x; i < NDI / 8; i += stride) {
    uint4 f = a8[i];
    unsigned uu[4] = {f.x, f.y, f.z, f.w};
#pragma unroll
    for (int c = 0; c < 8; ++c) {
      unsigned hb = (uu[c >> 1] >> ((c & 1) * 16)) & 0xFFFFu;
      if (hb && !(hb & 0x8000u) && (hb >> 5) >= b1) {
        unsigned p = atomicAdd(&sCnt, 1u);
        if (p < (unsigned)CSTAGE) { sIdx[p] = (unsigned)(i * 8 + c); sVal[p] = b2f((u16)hb); }
        else {
          unsigned g = atomicAdd(&scalU[12], 1u);
          if (g < (unsigned)CANDCAP) { candI[g] = (unsigned)(i * 8 + c); candV[g] = b2f((u16)hb); }
        }
      }
    }
  }
  __syncthreads();
  unsigned n = sCnt < (unsigned)CSTAGE ? sCnt : (unsigned)CSTAGE;
  if (threadIdx.x == 0) sBase = atomicAdd(&scalU[12], n);
  __syncthreads();
  unsigned base = sBase;
  for (unsigned j = threadIdx.x; j < n; j += 256) {
    unsigned g = base + j;
    if (g < (unsigned)CANDCAP) { candI[g] = sIdx[j]; candV[g] = sVal[j]; }
  }
}

// -------- refine level 2: multi-block histogram over candidates --------
__global__ __launch_bounds__(256) void k_rhist2(const unsigned* __restrict__ scalU,
    const float* __restrict__ candV, unsigned* __restrict__ h16)
{
  __shared__ unsigned lh[2048];
  for (int j = threadIdx.x; j < 2048; j += 256) lh[j] = 0;
  __syncthreads();
  unsigned b1 = scalU[0];
  int n = (int)scalU[12]; if (n > CANDCAP) n = CANDCAP;
  int stride = gridDim.x * blockDim.x;
  for (int j = blockIdx.x * 256 + threadIdx.x; j < n; j += stride) {
    unsigned u = __float_as_uint(candV[j]);
    if ((u >> 21) == b1) atomicAdd(&lh[(u >> 10) & 0x7FFu], 1u);
  }
  __syncthreads();
  unsigned* dst = h16 + (size_t)(blockIdx.x & (NREP - 1)) * 2048;
  for (int j = threadIdx.x; j < 2048; j += 256) {
    unsigned c = lh[j];
    if (c) atomicAdd(&dst[j], c);
  }
}

__global__ __launch_bounds__(256) void k_rscan2(unsigned* scalU, const unsigned* __restrict__ h16)
{
  __shared__ unsigned hsum[2048];
  __shared__ unsigned sscan[256];
  __shared__ int s_b; __shared__ unsigned s_cnt;
  int t = threadIdx.x;
  for (int j = t; j < 2048; j += 256) {
    unsigned s = 0;
#pragma unroll
    for (int r = 0; r < NREP; ++r) s += h16[r * 2048 + j];
    hsum[j] = s;
  }
  if (t == 0) { s_b = 0; s_cnt = 0; }
  __syncthreads();
  findBin(hsum, 2048, TOPK_TOTAL, scalU[1], sscan, &s_b, &s_cnt);
  if (t == 0) { scalU[2] = (unsigned)s_b; scalU[3] = s_cnt; }
}

// -------- refine level 3 --------
__global__ __launch_bounds__(256) void k_rhist3(const unsigned* __restrict__ scalU,
    const float* __restrict__ candV, unsigned* __restrict__ h16)
{
  __shared__ unsigned lh[1024];
  for (int j = threadIdx.x; j < 1024; j += 256) lh[j] = 0;
  __syncthreads();
  unsigned b1 = scalU[0], b2 = scalU[2];
  int n = (int)scalU[12]; if (n > CANDCAP) n = CANDCAP;
  int stride = gridDim.x * blockDim.x;
  for (int j = blockIdx.x * 256 + threadIdx.x; j < n; j += stride) {
    unsigned u = __float_as_uint(candV[j]);
    if ((u >> 21) == b1 && ((u >> 10) & 0x7FFu) == b2) atomicAdd(&lh[u & 0x3FFu], 1u);
  }
  __syncthreads();
  unsigned* dst = h16 + (size_t)(blockIdx.x & (NREP - 1)) * 1024;
  for (int j = threadIdx.x; j < 1024; j += 256) {
    unsigned c = lh[j];
    if (c) atomicAdd(&dst[j], c);
  }
}

__global__ __launch_bounds__(256) void k_rscan3(unsigned* scalU, const unsigned* __restrict__ h16)
{
  __shared__ unsigned hsum[1024];
  __shared__ unsigned sscan[256];
  __shared__ int s_b; __shared__ unsigned s_cnt;
  int t = threadIdx.x;
  for (int j = t; j < 1024; j += 256) {
    unsigned s = 0;
#pragma unroll
    for (int r = 0; r < NREP; ++r) s += h16[r * 1024 + j];
    hsum[j] = s;
  }
  if (t == 0) { s_b = 0; s_cnt = 0; }
  __syncthreads();
  findBin(hsum, 1024, TOPK_TOTAL, scalU[3], sscan, &s_b, &s_cnt);
  if (t == 0) {
    unsigned cut = (scalU[0] << 21) | (scalU[2] << 10) | (unsigned)s_b;
    scalU[4] = cut; scalU[5] = s_cnt; scalU[6] = TOPK_TOTAL - s_cnt;
  }
}

// -------- tie collection (multi-block) + resolve (tiny single-block) --------
__global__ __launch_bounds__(256) void k_tiecol(unsigned* scalU,
    const unsigned* __restrict__ candI, const float* __restrict__ candV,
    unsigned* __restrict__ tieB)
{
  unsigned cut = scalU[4];
  int n = (int)scalU[12]; if (n > CANDCAP) n = CANDCAP;
  int stride = gridDim.x * blockDim.x;
  for (int j = blockIdx.x * 256 + threadIdx.x; j < n; j += stride) {
    if (__float_as_uint(candV[j]) == cut) {
      unsigned p = atomicAdd(&scalU[14], 1u);
      if (p < (unsigned)TIECAP) tieB[p] = candI[j];
    }
  }
}

__global__ __launch_bounds__(256) void k_tieres(unsigned* scalU, const unsigned* __restrict__ tieB)
{
  __shared__ unsigned tbuf[TIECAP];
  __shared__ int sthr;
  int t = threadIdx.x;
  int m = (int)scalU[14]; if (m > TIECAP) m = TIECAP;
  int need = (int)scalU[6];
  for (int j = t; j < m; j += 256) tbuf[j] = tieB[j];
  if (t == 0) sthr = 0x7FFFFFFF;
  __syncthreads();
  if (need < m) {
    for (int ci = t; ci < m; ci += 256) {
      unsigned me = tbuf[ci];
      int r = 0;
      for (int j = 0; j < m; ++j) r += (tbuf[j] < me) ? 1 : 0;
      if (r == need - 1) sthr = (int)me;
    }
  }
  __syncthreads();
  if (t == 0) scalU[7] = (unsigned)sthr;
}

// -------- selection over candidates: per-row lists, col flags, l1/l0 --------
__global__ __launch_bounds__(256) void k_s1b(unsigned* scalU,
    const unsigned* __restrict__ candI, const float* __restrict__ candV,
    unsigned* rowCnt, unsigned* rlc, float* rlv, unsigned* colAct, double* scalD)
{
  __shared__ float redf[256];
  __shared__ unsigned redu[256];
  unsigned cut = scalU[4]; int tthr = (int)scalU[7];
  int n = (int)scalU[12]; if (n > CANDCAP) n = CANDCAP;
  float l1 = 0.f; unsigned l0 = 0;
  int stride = gridDim.x * blockDim.x;
  for (int j = blockIdx.x * 256 + threadIdx.x; j < n; j += stride) {
    float v = candV[j];
    unsigned u = __float_as_uint(v);
    unsigned idx = candI[j];
    if (u > cut || (u == cut && (int)idx <= tthr)) {
      int row = (int)(idx >> 15), col = (int)(idx & (D - 1));
      unsigned slot = atomicAdd(&rowCnt[row], 1u);
      if (slot < ROWCAP) {
        rlc[(size_t)row * ROWCAP + slot] = (unsigned)col;
        rlv[(size_t)row * ROWCAP + slot] = v;
      }
      colAct[col] = 1u;
      l1 += v; l0++;
    }
  }
  float l1s = bsumf(l1, redf);
  unsigned l0s = bsumu(l0, redu);
  if (threadIdx.x == 0) { atomicAdd(&scalD[0], (double)l1s); atomicAdd(&scalU[9], l0s); }
}

// -------- scatter selected into zeroed acts_topk (fp32 view) --------
__global__ __launch_bounds__(256) void k_scatter(const unsigned* __restrict__ scalU,
    const unsigned* __restrict__ candI, const float* __restrict__ candV, float* __restrict__ acts)
{
  unsigned cut = scalU[4]; int tthr = (int)scalU[7];
  int n = (int)scalU[12]; if (n > CANDCAP) n = CANDCAP;
  int stride = gridDim.x * blockDim.x;
  for (int j = blockIdx.x * 256 + threadIdx.x; j < n; j += stride) {
    float v = candV[j];
    unsigned u = __float_as_uint(v);
    unsigned idx = candI[j];
    if (u > cut || (u == cut && (int)idx <= tthr)) acts[idx] = v;
  }
}

// -------- dead-column bitmask + num_dead_features --------
__global__ __launch_bounds__(256) void k_dead(const unsigned* __restrict__ colAct,
    const float* __restrict__ nbna, unsigned* deadCols, unsigned* scalU,
    u64* __restrict__ dmask, unsigned* __restrict__ dbase)
{
  __shared__ unsigned scan[256];
  __shared__ unsigned svd;
  const int t = threadIdx.x;
  if (t == 0) svd = 0;
  __syncthreads();
  const int c0 = t * 128;
  u64 w0 = 0, w1 = 0;
  unsigned vd = 0;
  for (int i = 0; i < 64; ++i) {
    int c = c0 + i;
    bool act = colAct[c] != 0;
    float f = nbna[c] + 1.0f;
    if (!act && f >= 5.0f) w0 |= (1ull << i);
    vd += (!act && f > 5.0f) ? 1u : 0u;
  }
  for (int i = 0; i < 64; ++i) {
    int c = c0 + 64 + i;
    bool act = colAct[c] != 0;
    float f = nbna[c] + 1.0f;
    if (!act && f >= 5.0f) w1 |= (1ull << i);
    vd += (!act && f > 5.0f) ? 1u : 0u;
  }
  unsigned cnt = (unsigned)(__popcll(w0) + __popcll(w1));
  scan[t] = cnt; __syncthreads();
  for (int o = 1; o < 256; o <<= 1) {
    unsigned xx = (t >= o) ? scan[t - o] : 0u; __syncthreads();
    scan[t] += xx; __syncthreads();
  }
  unsigned p = scan[t] - cnt;
  dmask[2 * t] = w0; dmask[2 * t + 1] = w1;
  dbase[2 * t] = p; dbase[2 * t + 1] = p + (unsigned)__popcll(w0);
  atomicAdd(&svd, vd);
  __syncthreads();
  if (t == 255) scalU[10] = scan[255];
  if (t == 0) scalU[11] = svd;
  (void)deadCols;
}

// -------- per-row aux top-512 over bf16 acts: 2 streaming passes + LDS refine --------
__global__ __launch_bounds__(256) void k_auxsel(const u16* __restrict__ actsb,
    const unsigned* __restrict__ scalU, const u64* __restrict__ dmask,
    unsigned* auxC, float* auxV, unsigned* auxN)
{
  __shared__ u64 smask[512];           // 4 KB
  __shared__ unsigned hist[2048];      // 8 KB
  __shared__ unsigned sscan[256];      // 1 KB
  __shared__ float tval[SCAP];         // 12 KB
  __shared__ unsigned tcol[SCAP];      // 12 KB
  __shared__ int s_b; __shared__ unsigned s_cnt;
  __shared__ unsigned s_sel, s_tm;
  const int row = blockIdx.x, t = threadIdx.x;
  const uint4* arow8 = (const uint4*)(actsb + (size_t)row * D);

  for (int j = t; j < 512; j += 256) smask[j] = dmask[j];
  for (int j = t; j < 2048; j += 256) hist[j] = 0;
  if (t == 0) { s_sel = 0; s_tm = 0; s_b = 0; s_cnt = 0; }
  __syncthreads();

  // pass 1: positive count + level-1 (11-bit) histogram
  unsigned pcnt = 0;
  for (int j = t; j < D / 8; j += 256) {
    uint4 f = arow8[j];
    u64 w = smask[j >> 3];
    int sh = (j & 7) * 8;
    unsigned uu[4] = {f.x, f.y, f.z, f.w};
#pragma unroll
    for (int c = 0; c < 8; ++c) {
      unsigned hb = (uu[c >> 1] >> ((c & 1) * 16)) & 0xFFFFu;
      if (((w >> (sh + c)) & 1ull) && hb && !(hb & 0x8000u)) {
        pcnt++;
        atomicAdd(&hist[hb >> 5], 1u);
      }
    }
  }
  unsigned P = bsumu(pcnt, sscan);
  unsigned* outC = auxC + (size_t)row * TOPK_AUX;
  float* outV = auxV + (size_t)row * TOPK_AUX;

  if (P <= (unsigned)TOPK_AUX) {
    for (int j = t; j < D / 8; j += 256) {
      uint4 f = arow8[j];
      u64 w = smask[j >> 3];
      int sh = (j & 7) * 8;
      unsigned uu[4] = {f.x, f.y, f.z, f.w};
#pragma unroll
      for (int c = 0; c < 8; ++c) {
        unsigned hb = (uu[c >> 1] >> ((c & 1) * 16)) & 0xFFFFu;
        if (((w >> (sh + c)) & 1ull) && hb && !(hb & 0x8000u)) {
          unsigned s = atomicAdd(&s_sel, 1u);
          outC[s] = (unsigned)(j * 8 + c); outV[s] = b2f((u16)hb);
        }
      }
    }
    __syncthreads();
    if (t == 0) auxN[row] = s_sel;
    return;
  }

  __syncthreads();
  findBin(hist, 2048, (unsigned)TOPK_AUX, 0u, sscan, &s_b, &s_cnt);
  unsigned b1 = (unsigned)s_b, c1 = s_cnt;

  // pass 2: bin > b1 -> emit; bin == b1 -> stage to LDS
  for (int j = t; j < D / 8; j += 256) {
    uint4 f = arow8[j];
    u64 w = smask[j >> 3];
    int sh = (j & 7) * 8;
    unsigned uu[4] = {f.x, f.y, f.z, f.w};
#pragma unroll
    for (int c = 0; c < 8; ++c) {
      unsigned hb = (uu[c >> 1] >> ((c & 1) * 16)) & 0xFFFFu;
      if (((w >> (sh + c)) & 1ull) && hb && !(hb & 0x8000u)) {
        unsigned bin = hb >> 5;
        if (bin > b1) {
          unsigned s = atomicAdd(&s_sel, 1u);
          outC[s] = (unsigned)(j * 8 + c); outV[s] = b2f((u16)hb);
        } else if (bin == b1) {
          unsigned p = atomicAdd(&s_tm, 1u);
          if (p < (unsigned)SCAP) { tcol[p] = (unsigned)(j * 8 + c); tval[p] = b2f((u16)hb); }
        }
      }
    }
  }
  __syncthreads();
  int m = (int)s_tm;

  if (m <= SCAP) {
    for (int j = t; j < 2048; j += 256) hist[j] = 0;
    if (t == 0) { s_b = 0; s_cnt = 0; }
    __syncthreads();
    for (int j = t; j < m; j += 256)
      atomicAdd(&hist[(__float_as_uint(tval[j]) >> 10) & 0x7FFu], 1u);
    __syncthreads();
    findBin(hist, 2048, (unsigned)TOPK_AUX, c1, sscan, &s_b, &s_cnt);
    unsigned b2 = (unsigned)s_b, c2 = s_cnt;
    for (int j = t; j < 1024; j += 256) hist[j] = 0;
    if (t == 0) { s_b = 0; s_cnt = 0; }
    __syncthreads();
    for (int j = t; j < m; j += 256) {
      unsigned u = __float_as_uint(tval[j]);
      if (((u >> 10) & 0x7FFu) == b2) atomicAdd(&hist[u & 0x3FFu], 1u);
    }
    __syncthreads();
    findBin(hist, 1024, (unsigned)TOPK_AUX, c2, sscan, &s_b, &s_cnt);
    unsigned cut = (b1 << 21) | (b2 << 10) | (unsigned)s_b;
    int need = TOPK_AUX - (int)s_cnt;
    for (int j = t; j < m; j += 256) {
      unsigned u = __float_as_uint(tval[j]);
      if (u > cut) {
        unsigned s = atomicAdd(&s_sel, 1u);
        outC[s] = tcol[j]; outV[s] = tval[j];
      } else if (u == cut) {
        unsigned col = tcol[j];
        int r = 0;
        for (int k = 0; k < m; ++k)
          r += (__float_as_uint(tval[k]) == cut && tcol[k] < col) ? 1 : 0;
        if (r < need) { unsigned s = atomicAdd(&s_sel, 1u); outC[s] = col; outV[s] = tval[j]; }
      }
    }
    __syncthreads();
    if (t == 0) auxN[row] = s_sel;
    return;
  }

  // ---- fallback (staged overflow): global streaming refine, exact ----
  for (int j = t; j < 2048; j += 256) hist[j] = 0;
  if (t == 0) { s_b = 0; s_cnt = 0; }
  __syncthreads();
  for (int j = t; j < D / 8; j += 256) {
    uint4 f = arow8[j];
    u64 w = smask[j >> 3];
    int sh = (j & 7) * 8;
    unsigned uu[4] = {f.x, f.y, f.z, f.w};
#pragma unroll
    for (int c = 0; c < 8; ++c) {
      unsigned hb = (uu[c >> 1] >> ((c & 1) * 16)) & 0xFFFFu;
      if (((w >> (sh + c)) & 1ull) && hb && !(hb & 0x8000u)) {
        if ((hb >> 5) == b1) atomicAdd(&hist[((hb << 16) >> 10) & 0x7FFu], 1u);
      }
    }
  }
  __syncthreads();
  findBin(hist, 2048, (unsigned)TOPK_AUX, c1, sscan, &s_b, &s_cnt);
  unsigned b2 = (unsigned)s_b, c2 = s_cnt;
  __syncthreads();
  unsigned cut = (b1 << 21) | (b2 << 10);  // bf16 values have zero low 10 bits
  int need = TOPK_AUX - (int)c2;
  if (t == 0) s_tm = 0;
  __syncthreads();
  for (int j = t; j < D / 8; j += 256) {
    uint4 f = arow8[j];
    u64 w = smask[j >> 3];
    int sh = (j & 7) * 8;
    unsigned uu[4] = {f.x, f.y, f.z, f.w};
#pragma unroll
    for (int c = 0; c < 8; ++c) {
      unsigned hb = (uu[c >> 1] >> ((c & 1) * 16)) & 0xFFFFu;
      if (((w >> (sh + c)) & 1ull) && hb && !(hb & 0x8000u)) {
        unsigned u = hb << 16;
        if (u > cut) {
          unsigned s = atomicAdd(&s_sel, 1u);
          outC[s] = (unsigned)(j * 8 + c); outV[s] = __uint_as_float(u);
        } else if (u == cut) {
          unsigned p = atomicAdd(&s_tm, 1u);
          if (p < (unsigned)SCAP) tcol[p] = (unsigned)(j * 8 + c);
        }
      }
    }
  }
  __syncthreads();
  int mm = (int)s_tm; if (mm > SCAP) mm = SCAP;
  float cv = __uint_as_float(cut);
  for (int ci = t; ci < mm; ci += 256) {
    unsigned col = tcol[ci];
    int r = 0;
    for (int j = 0; j < mm; ++j) r += (tcol[j] < col) ? 1 : 0;
    if (r < need) { unsigned s = atomicAdd(&s_sel, 1u); outC[s] = col; outV[s] = cv; }
  }
  __syncthreads();
  if (t == 0) auxN[row] = s_sel;
}

// -------- sparse matryoshka decode (bf16 Wdec) + per-group MSE + sae_out + residual --------
__global__ __launch_bounds__(256) void k_decode(const u16* __restrict__ Wdecb,
    const float* __restrict__ bdec, const float* __restrict__ xn,
    const unsigned* __restrict__ rowCnt, const unsigned* __restrict__ rlc,
    const float* __restrict__ rlv, const float* __restrict__ rmean,
    const float* __restrict__ rstd, float* __restrict__ sae,
    float* __restrict__ resid, double* scalD)
{
  __shared__ int tlc[ROWCAP]; __shared__ float tlv[ROWCAP];
  __shared__ int slc[ROWCAP]; __shared__ float slv[ROWCAP];
  __shared__ int gcnt[5], gpos[5], gend[5];
  __shared__ float red[256];
  const int row = blockIdx.x, t = threadIdx.x;
  int cnt = (int)rowCnt[row]; if (cnt > ROWCAP) cnt = ROWCAP;
  if (t < 5) gcnt[t] = 0;
  __syncthreads();
  for (int e = t; e < cnt; e += 256) {
    int c = (int)rlc[(size_t)row * ROWCAP + e];
    tlc[e] = c; tlv[e] = rlv[(size_t)row * ROWCAP + e];
    int ilog = 31 - __clz(c | 1);
    int g = ilog > 10 ? ilog - 10 : 0;
    atomicAdd(&gcnt[g], 1);
  }
  __syncthreads();
  if (t == 0) {
    int b = 0;
    for (int g = 0; g < 5; ++g) { gpos[g] = b; b += gcnt[g]; gend[g] = b; }
  }
  __syncthreads();
  for (int e = t; e < cnt; e += 256) {
    int c = tlc[e];
    int ilog = 31 - __clz(c | 1);
    int g = ilog > 10 ? ilog - 10 : 0;
    int p = atomicAdd(&gpos[g], 1);
    slc[p] = c; slv[p] = tlv[e];
  }
  __syncthreads();
  float r0 = bdec[t], r1 = bdec[t + 256], r2 = bdec[t + 512];
  size_t o = (size_t)row * DIN;
  float x0 = xn[o + t], x1 = xn[o + t + 256], x2 = xn[o + t + 512];
  int e = 0;
#pragma unroll 1
  for (int g = 0; g < 5; ++g) {
    int e1 = gend[g];
#pragma unroll 2
    for (; e < e1; ++e) {
      int c = slc[e]; float v = slv[e];
      const u16* w = Wdecb + (size_t)c * DIN;
      r0 = fmaf(v, b2f(w[t]), r0);
      r1 = fmaf(v, b2f(w[t + 256]), r1);
      r2 = fmaf(v, b2f(w[t + 512]), r2);
    }
    float dd0 = r0 - x0, dd1 = r1 - x1, dd2 = r2 - x2;
    float sq = bsumf(dd0 * dd0 + dd1 * dd1 + dd2 * dd2, red);
    if (t == 0) atomicAdd(&scalD[4 + g], (double)sq);
  }
  float m = rmean[row], sd = rstd[row];
  sae[o + t] = r0 * sd + m; sae[o + t + 256] = r1 * sd + m; sae[o + t + 512] = r2 * sd + m;
  resid[o + t] = x0 - r0; resid[o + t + 256] = x1 - r1; resid[o + t + 512] = x2 - r2;
}

// -------- aux decode (bf16 Wdec) + aux MSE --------
__global__ __launch_bounds__(256) void k_auxdec(const u16* __restrict__ Wdecb,
    const unsigned* __restrict__ auxC, const float* __restrict__ auxV,
    const unsigned* __restrict__ auxN, const float* __restrict__ resid, double* scalD)
{
  __shared__ int lc[TOPK_AUX]; __shared__ float lv[TOPK_AUX];
  __shared__ float red[256];
  const int row = blockIdx.x, t = threadIdx.x;
  int cnt = (int)auxN[row]; if (cnt > TOPK_AUX) cnt = TOPK_AUX;
  for (int e = t; e < cnt; e += 256) {
    lc[e] = (int)auxC[(size_t)row * TOPK_AUX + e];
    lv[e] = auxV[(size_t)row * TOPK_AUX + e];
  }
  __syncthreads();
  float a0 = 0.f, a1 = 0.f, a2 = 0.f;
#pragma unroll 4
  for (int e = 0; e < cnt; ++e) {
    int c = lc[e]; float v = lv[e];
    const u16* w = Wdecb + (size_t)c * DIN;
    a0 = fmaf(v, b2f(w[t]), a0);
    a1 = fmaf(v, b2f(w[t + 256]), a1);
    a2 = fmaf(v, b2f(w[t + 512]), a2);
  }
  size_t o = (size_t)row * DIN;
  float s0 = resid[o + t], s1 = resid[o + t + 256], s2 = resid[o + t + 512];
  float d0 = a0 - s0, d1 = a1 - s1, d2 = a2 - s2;
  float sq = bsumf(d0 * d0 + d1 * d1 + d2 * d2, red);
  float ab = bsumf(fabsf(a0) + fabsf(a1) + fabsf(a2), red);
  if (t == 0) { atomicAdd(&scalD[9], (double)sq); atomicAdd(&scalD[10], (double)ab); }
}

// -------- scalar finalize --------
__global__ void k_final(const unsigned* __restrict__ scalU, const double* __restrict__ scalD,
                        const float* __restrict__ thr, float* __restrict__ out)
{
  if (threadIdx.x != 0 || blockIdx.x != 0) return;
  const double NEL = (double)B * (double)DIN;
  double term0 = scalD[3] / NEL;
  double tot = term0;
  double mn = 1e300, mx = -1e300;
  for (int g = 0; g < 5; ++g) {
    double l2 = scalD[4 + g] / NEL;
    tot += l2;
    mn = l2 < mn ? l2 : mn;
    mx = l2 > mx ? l2 : mx;
  }
  double mean_l2 = tot / 6.0;
  double sum = scalD[1], ssq = scalD[2];
  double xvar = (ssq - sum * sum / NEL) / (NEL - 1.0);
  double fvu = mean_l2 / (xvar + 1e-10);
  double l1n = scalD[0] / (double)B;
  double l1loss = (double)0.0003f * l1n;
  double l0n = (double)scalU[9] / (double)B;
  double auxmse = scalD[9] / NEL;
  double auxloss = (scalD[10] > 0.0) ? 0.03125 * auxmse : 0.0;
  double loss = mean_l2 + l1loss + auxloss;
  float cutv = __uint_as_float(scalU[4]);
  float t0 = thr[0];
  float newthr = (scalU[9] > 0u) ? (0.99f * t0 + 0.01f * cutv) : t0;
  float* s = out + (size_t)B * DIN + (size_t)NDI;
  s[0] = (float)loss;   s[1] = (float)l1loss; s[2] = (float)mean_l2;
  s[3] = (float)mn;     s[4] = (float)mx;     s[5] = (float)l0n;
  s[6] = (float)l1n;    s[7] = (float)auxloss; s[8] = newthr;
  s[9] = (float)fvu;    s[10] = (float)scalU[11];
}

extern "C" void kernel_launch(void* const* d_in, const int* in_sizes, int n_in,
                              void* d_out, int out_size, void* d_ws, size_t ws_size,
                              hipStream_t stream)
{
  (void)in_sizes; (void)n_in; (void)out_size; (void)ws_size;
  const float* x    = (const float*)d_in[0];
  const float* Wenc = (const float*)d_in[1];
  const float* Wdec = (const float*)d_in[2];
  const float* bdec = (const float*)d_in[3];
  const float* nbna = (const float*)d_in[4];
  const float* thr  = (const float*)d_in[5];
  float* out = (float*)d_out;
  char* ws = (char*)d_ws;

  float* sae  = out;
  float* acts = out + (size_t)B * DIN;     // acts_topk fp32 output region
  u16*  actsb = (u16*)(out + (size_t)B * DIN);  // bf16 dense acts (first half of region)

  unsigned* hist1 = (unsigned*)(ws + OFF_HIST1);
  unsigned* hist2 = (unsigned*)(ws + OFF_HIST2);
  unsigned* hist3 = (unsigned*)(ws + OFF_HIST3);
  unsigned* hist4 = (unsigned*)(ws + OFF_HIST4);
  unsigned* scalU = (unsigned*)(ws + OFF_SCALU);
  double*   scalD = (double*)(ws + OFF_SCALD);
  unsigned* rowCnt= (unsigned*)(ws + OFF_ROWCNT);
  unsigned* auxN  = (unsigned*)(ws + OFF_AUXCNT);
  unsigned* colAct= (unsigned*)(ws + OFF_COLACT);
  float* xn    = (float*)(ws + OFF_XN);
  float* resid = (float*)(ws + OFF_RES);
  float* rmean = (float*)(ws + OFF_RMEAN);
  float* rstd  = (float*)(ws + OFF_RSTD);
  u16*   xncb  = (u16*)(ws + OFF_XNCB);
  unsigned* deadC = (unsigned*)(ws + OFF_DEAD);
  u64*      dmask = (u64*)(ws + OFF_DMASK);
  unsigned* dbase = (unsigned*)(ws + OFF_DBASE);
  unsigned* rlc = (unsigned*)(ws + OFF_RLC);
  float*    rlv = (float*)(ws + OFF_RLV);
  unsigned* auxC = (unsigned*)(ws + OFF_AXC);
  float*    auxV = (float*)(ws + OFF_AXV);
  unsigned* candI = (unsigned*)(ws + OFF_CANDI);
  float*    candV = (float*)(ws + OFF_CANDV);
  unsigned* tieB  = (unsigned*)(ws + OFF_TIEB);
  u16* Wt    = (u16*)(ws + OFF_WT);   // WencT bf16, later reused as Wdec bf16
  u16* Wdecb = (u16*)(ws + OFF_WT);

  hipMemsetAsync(ws, 0, ZERO_BYTES, stream);
  hipLaunchKernelGGL(k_rowstats, dim3(B), dim3(256), 0, stream, x, bdec, xn, xncb, rmean, rstd, scalD);
  hipLaunchKernelGGL(k_wt, dim3(D / 64, DIN / 64), dim3(256), 0, stream, Wenc, Wt);
  hipLaunchKernelGGL(k_gemm, dim3(D / 128, B / 128), dim3(256), 0, stream, xncb, Wt, actsb, hist1, scalU, candI, candV);
  hipLaunchKernelGGL(k_scan1a, dim3(1), dim3(256), 0, stream, scalU, hist1);
  hipLaunchKernelGGL(k_histfull, dim3(2048), dim3(256), 0, stream, (const uint4*)actsb, scalU, hist2);
  hipLaunchKernelGGL(k_scan1b, dim3(1), dim3(256), 0, stream, scalU, hist2);
  hipLaunchKernelGGL(k_compact, dim3(2048), dim3(256), 0, stream, (const uint4*)actsb, scalU, candI, candV);
  hipLaunchKernelGGL(k_wdecb, dim3(2048), dim3(256), 0, stream, (const float4*)Wdec, Wdecb);
  hipLaunchKernelGGL(k_rhist2, dim3(256), dim3(256), 0, stream, scalU, candV, hist3);
  hipLaunchKernelGGL(k_rscan2, dim3(1), dim3(256), 0, stream, scalU, hist3);
  hipLaunchKernelGGL(k_rhist3, dim3(256), dim3(256), 0, stream, scalU, candV, hist4);
  hipLaunchKernelGGL(k_rscan3, dim3(1), dim3(256), 0, stream, scalU, hist4);
  hipLaunchKernelGGL(k_tiecol, dim3(256), dim3(256), 0, stream, scalU, candI, candV, tieB);
  hipLaunchKernelGGL(k_tieres, dim3(1), dim3(256), 0, stream, scalU, tieB);
  hipLaunchKernelGGL(k_s1b, dim3(256), dim3(256), 0, stream, scalU, candI, candV, rowCnt, rlc, rlv, colAct, scalD);
  hipLaunchKernelGGL(k_dead, dim3(1), dim3(256), 0, stream, colAct, nbna, deadC, scalU, dmask, dbase);
  hipLaunchKernelGGL(k_auxsel, dim3(B), dim3(256), 0, stream, actsb, scalU, dmask, auxC, auxV, auxN);
  hipMemsetAsync(acts, 0, (size_t)NDI * 4, stream);
  hipLaunchKernelGGL(k_scatter, dim3(256), dim3(256), 0, stream, scalU, candI, candV, acts);
  hipLaunchKernelGGL(k_decode, dim3(B), dim3(256), 0, stream, Wdecb, bdec, xn, rowCnt, rlc, rlv, rmean, rstd, sae, resid, scalD);
  hipLaunchKernelGGL(k_auxdec, dim3(B), dim3(256), 0, stream, Wdecb, auxC, auxV, auxN, resid, scalD);
  hipLaunchKernelGGL(k_final, dim3(1), dim3(64), 0, stream, scalU, scalD, thr, out);
}

// Round 11
// 907.699 us; speedup vs baseline: 1.0771x; 1.0666x over previous
//
#include <hip/hip_runtime.h>
#include <stdint.h>

#define DEVFN static __device__ __forceinline__

typedef unsigned short u16;
typedef unsigned long long u64;
typedef short short8 __attribute__((ext_vector_type(8)));
typedef float vf4 __attribute__((ext_vector_type(4)));

constexpr int B = 2048;
constexpr int DIN = 768;
constexpr int D = 32768;
constexpr int NDI = B * D;                 // 67,108,864
constexpr unsigned TOPK_TOTAL = 65536u;    // 32 * B
constexpr int TOPK_AUX = 512;
constexpr int ROWCAP = 512;
constexpr int CANDCAP = 2097152;
constexpr int CSTAGE = 4096;
constexpr int TIECAP = 4096;
constexpr int SCAP = 3072;                 // aux boundary-bin LDS stage cap
constexpr int NREP = 16;                   // global histogram replicas

// ---------------- workspace layout (bytes) ----------------
constexpr size_t OFF_HIST1  = 0;                          // 16 x 8192 (level-1, from GEMM)
constexpr size_t OFF_HIST2  = 131072;                     // 16 x 8192 (fallback full hist)
constexpr size_t OFF_HIST3  = 262144;                     // 16 x 8192 (refine level-2)
constexpr size_t OFF_HIST4  = 393216;                     // 16 x 4096 (refine level-3)
constexpr size_t OFF_SCALU  = 458752;                     // u32[64]
constexpr size_t OFF_SCALD  = 459008;                     // double[32]
constexpr size_t OFF_ROWCNT = 459264;                     // 8192
constexpr size_t OFF_AUXCNT = 467456;                     // 8192
constexpr size_t OFF_COLACT = 475648;                     // 131072
constexpr size_t ZERO_BYTES = 606720;
constexpr size_t OFF_XN    = ZERO_BYTES;                  // 6291456
constexpr size_t OFF_RES   = OFF_XN   + 6291456;          // 6291456
constexpr size_t OFF_RMEAN = OFF_RES  + 6291456;          // 8192
constexpr size_t OFF_RSTD  = OFF_RMEAN + 8192;            // 8192
constexpr size_t OFF_XNCB  = OFF_RSTD + 8192;             // 3145728 (bf16 xnc)
constexpr size_t OFF_DEAD  = OFF_XNCB + 3145728;          // 131072
constexpr size_t OFF_DMASK = OFF_DEAD + 131072;           // 4096  (512 x u64 dead bitmask)
constexpr size_t OFF_DBASE = OFF_DMASK + 4096;            // 2048  (512 x u32 prefix base)
constexpr size_t OFF_RLC   = OFF_DBASE + 2048;            // 4194304
constexpr size_t OFF_RLV   = OFF_RLC  + 4194304;          // 4194304
constexpr size_t OFF_AXC   = OFF_RLV  + 4194304;          // 4194304
constexpr size_t OFF_AXV   = OFF_AXC  + 4194304;          // 4194304
constexpr size_t OFF_CANDI = OFF_AXV  + 4194304;          // 8388608
constexpr size_t OFF_CANDV = OFF_CANDI + (size_t)CANDCAP * 4; // 8388608
constexpr size_t OFF_TIEB  = OFF_CANDV + (size_t)CANDCAP * 4; // 16384
constexpr size_t OFF_WT    = OFF_TIEB + (size_t)TIECAP * 4;   // 50331648 (WencT bf16; reused as Wdec bf16)

// scalU: 0 b1, 1 cntgt1, 2 b2, 3 cntgt2, 4 cutoff_bits, 5 cntgt_final, 6 need,
//        7 tie_thr(i32), 9 l0_count, 10 n_dead, 11 num_dead_feat, 12 cand_count,
//        13 needFull, 14 tie_count
// scalD: 0 l1_sum, 1 sum_xn, 2 sumsq_xn, 3 sq0, 4..8 group_sq[5], 9 aux_sq, 10 aux_abs

DEVFN u16 f2bf(float f) {
  unsigned u = __float_as_uint(f);
  unsigned r = (u + 0x7FFFu + ((u >> 16) & 1u)) >> 16;
  return (u16)r;
}
DEVFN float b2f(u16 h) { return __uint_as_float(((unsigned)h) << 16); }

DEVFN float bsumf(float v, float* red) {
  int t = threadIdx.x;
  red[t] = v; __syncthreads();
  for (int o = 128; o > 0; o >>= 1) { if (t < o) red[t] += red[t + o]; __syncthreads(); }
  float r = red[0]; __syncthreads();
  return r;
}
DEVFN unsigned bsumu(unsigned v, unsigned* red) {
  int t = threadIdx.x;
  red[t] = v; __syncthreads();
  for (int o = 128; o > 0; o >>= 1) { if (t < o) red[t] += red[t + o]; __syncthreads(); }
  unsigned r = red[0]; __syncthreads();
  return r;
}
// 384-thread block sum via zero-padded 512-wide tree
DEVFN float bsumf2(float v, float* red) {
  int t = threadIdx.x;
  red[t] = v;
  if (t < 128) red[384 + t] = 0.f;
  __syncthreads();
  for (int o = 256; o > 0; o >>= 1) { if (t < o) red[t] += red[t + o]; __syncthreads(); }
  float r = red[0]; __syncthreads();
  return r;
}

// Find bin (scanning from the top) where cumulative count reaches K.
DEVFN void findBin(const unsigned* hist, int nb, unsigned K, unsigned base,
                   unsigned* sscan, int* s_b, unsigned* s_cnt)
{
  int t = threadIdx.x;
  int chunk = nb >> 8;
  int hi = nb - 1 - t * chunk;
  unsigned p = 0;
  for (int k = 0; k < chunk; ++k) p += hist[hi - k];
  sscan[t] = p; __syncthreads();
  for (int o = 1; o < 256; o <<= 1) {
    unsigned xx = (t >= o) ? sscan[t - o] : 0u; __syncthreads();
    sscan[t] += xx; __syncthreads();
  }
  unsigned incl = sscan[t], excl = incl - p;
  unsigned cum = base + excl;
  if (base + incl >= K && cum < K) {
    unsigned acc = cum;
    for (int k = 0; k < chunk; ++k) {
      unsigned h = hist[hi - k];
      if (acc + h >= K) { *s_b = hi - k; *s_cnt = acc; break; }
      acc += h;
    }
  }
  __syncthreads();
}

// -------- row stats + normalization (+ bf16 xnc) --------
__global__ __launch_bounds__(256) void k_rowstats(
    const float* __restrict__ x, const float* __restrict__ bdec,
    float* __restrict__ xn, u16* __restrict__ xncb,
    float* __restrict__ rmean, float* __restrict__ rstd, double* scalD)
{
  __shared__ float red[256];
  const int row = blockIdx.x, t = threadIdx.x;
  const float* xr = x + (size_t)row * DIN;
  float v0 = xr[t], v1 = xr[t + 256], v2 = xr[t + 512];
  float mean = bsumf(v0 + v1 + v2, red) * (1.0f / DIN);
  float d0 = v0 - mean, d1 = v1 - mean, d2 = v2 - mean;
  float var = bsumf(d0 * d0 + d1 * d1 + d2 * d2, red) * (1.0f / (DIN - 1));
  float sd = sqrtf(var);
  float inv = 1.0f / (sd + 1e-5f);
  float n0 = d0 * inv, n1 = d1 * inv, n2 = d2 * inv;
  size_t o = (size_t)row * DIN;
  xn[o + t] = n0; xn[o + t + 256] = n1; xn[o + t + 512] = n2;
  float b0 = bdec[t], b1 = bdec[t + 256], b2 = bdec[t + 512];
  xncb[o + t] = f2bf(n0 - b0); xncb[o + t + 256] = f2bf(n1 - b1); xncb[o + t + 512] = f2bf(n2 - b2);
  if (t == 0) { rmean[row] = mean; rstd[row] = sd; }
  float sxn = bsumf(n0 + n1 + n2, red);
  float ssq = bsumf(n0 * n0 + n1 * n1 + n2 * n2, red);
  float e0 = b0 - n0, e1 = b1 - n1, e2 = b2 - n2;
  float sq0 = bsumf(e0 * e0 + e1 * e1 + e2 * e2, red);
  if (t == 0) {
    atomicAdd(&scalD[1], (double)sxn);
    atomicAdd(&scalD[2], (double)ssq);
    atomicAdd(&scalD[3], (double)sq0);
  }
}

// -------- W_enc [768][32768] f32 -> Wt [32768][768] bf16 (transpose+convert) --------
__global__ __launch_bounds__(256) void k_wt(const float* __restrict__ W, u16* __restrict__ Wt)
{
  __shared__ float tl[64][65];
  const int t = threadIdx.x;
  const int n0 = blockIdx.x * 64, k0 = blockIdx.y * 64;
  const int rr = t >> 6, cc = t & 63;
#pragma unroll
  for (int r = 0; r < 16; ++r) {
    int kk = r * 4 + rr;
    tl[kk][cc] = W[(size_t)(k0 + kk) * D + n0 + cc];
  }
  __syncthreads();
#pragma unroll
  for (int r = 0; r < 16; ++r) {
    int nn = r * 4 + rr;
    Wt[(size_t)(n0 + nn) * DIN + k0 + cc] = f2bf(tl[cc][nn]);
  }
}

// -------- W_dec [32768][768] f32 -> bf16 (elementwise) --------
__global__ __launch_bounds__(256) void k_wdecb(const float4* __restrict__ W4, u16* __restrict__ Wb)
{
  int stride = gridDim.x * blockDim.x;
  const int n4 = (D * DIN) / 4;
  for (int i = blockIdx.x * 256 + threadIdx.x; i < n4; i += stride) {
    float4 f = W4[i];
    unsigned p0 = (unsigned)f2bf(f.x) | ((unsigned)f2bf(f.y) << 16);
    unsigned p1 = (unsigned)f2bf(f.z) | ((unsigned)f2bf(f.w) << 16);
    uint2 q; q.x = p0; q.y = p1;
    *(uint2*)&Wb[(size_t)i * 4] = q;
  }
}

// -------- encode GEMM: acts = relu(xnc @ Wenc), bf16 MFMA + thresholded histogram --------
// (round-8 measured-best configuration: fp32 C, bn on grid x)
__global__ __launch_bounds__(256) void k_gemm(const u16* __restrict__ A,
                                              const u16* __restrict__ Bt,
                                              float* __restrict__ C,
                                              unsigned* __restrict__ hist16)
{
  __shared__ __align__(16) char lds[32768];
  const int tid = threadIdx.x, lane = tid & 63, wid = tid >> 6;
  const int bn = blockIdx.x * 128, bm = blockIdx.y * 128;

  const char* pA[4]; const char* pB[4];
#pragma unroll
  for (int i = 0; i < 4; ++i) {
    int G = i * 256 + wid * 64 + lane;
    int r = G >> 3, c = (G & 7) ^ (r & 7);
    pA[i] = (const char*)(A + (size_t)(bm + r) * DIN + c * 8);
    pB[i] = (const char*)(Bt + (size_t)(bn + r) * DIN + c * 8);
  }
  int aoff[2][4], boff[2][4];
#pragma unroll
  for (int kc = 0; kc < 2; ++kc)
#pragma unroll
    for (int i = 0; i < 4; ++i) {
      int cs = kc * 4 + (lane >> 4);
      int rA = (wid >> 1) * 64 + i * 16 + (lane & 15);
      aoff[kc][i] = rA * 128 + ((cs ^ (rA & 7)) * 16);
      int rB = (wid & 1) * 64 + i * 16 + (lane & 15);
      boff[kc][i] = 16384 + rB * 128 + ((cs ^ (rB & 7)) * 16);
    }

  vf4 acc[4][4];
#pragma unroll
  for (int i = 0; i < 4; ++i)
#pragma unroll
    for (int j = 0; j < 4; ++j) acc[i][j] = (vf4)0.f;

  for (int ks = 0; ks < 12; ++ks) {
    __syncthreads();
#pragma unroll
    for (int i = 0; i < 4; ++i) {
      __builtin_amdgcn_global_load_lds(
          (const __attribute__((address_space(1))) void*)pA[i],
          (__attribute__((address_space(3))) void*)(lds + (i * 256 + wid * 64) * 16), 16, 0, 0);
      __builtin_amdgcn_global_load_lds(
          (const __attribute__((address_space(1))) void*)pB[i],
          (__attribute__((address_space(3))) void*)(lds + 16384 + (i * 256 + wid * 64) * 16), 16, 0, 0);
      pA[i] += 128; pB[i] += 128;
    }
    __syncthreads();
#pragma unroll
    for (int kc = 0; kc < 2; ++kc) {
      short8 av[4], bv[4];
#pragma unroll
      for (int i = 0; i < 4; ++i) {
        av[i] = *(const short8*)(lds + aoff[kc][i]);
        bv[i] = *(const short8*)(lds + boff[kc][i]);
      }
#pragma unroll
      for (int i = 0; i < 4; ++i)
#pragma unroll
        for (int j = 0; j < 4; ++j)
          acc[i][j] = __builtin_amdgcn_mfma_f32_16x16x32_bf16(av[i], bv[j], acc[i][j], 0, 0, 0);
    }
  }

  // epilogue: reuse LDS as a local 2048-bin histogram of values >= 1.0
  unsigned* h = (unsigned*)lds;
  __syncthreads();
  for (int j = tid; j < 2048; j += 256) h[j] = 0;
  __syncthreads();

  const int r0 = bm + (wid >> 1) * 64 + (lane >> 4) * 4;
  const int c0 = bn + (wid & 1) * 64 + (lane & 15);
#pragma unroll
  for (int i = 0; i < 4; ++i)
#pragma unroll
    for (int j = 0; j < 4; ++j) {
      float* cp = C + (size_t)(r0 + i * 16) * D + c0 + j * 16;
#pragma unroll
      for (int q = 0; q < 4; ++q) {
        float v = fmaxf(acc[i][j][q], 0.f);
        cp[(size_t)q * D] = v;
        if (v >= 1.0f) atomicAdd(&h[__float_as_uint(v) >> 21], 1u);
      }
    }
  __syncthreads();
  unsigned* dst = hist16 + (size_t)(blockIdx.x & (NREP - 1)) * 2048;
  for (int j = 508 + tid; j < 2048; j += 256) {
    unsigned c = h[j];
    if (c) atomicAdd(&dst[j], c);
  }
}

// -------- scan over thresholded histogram; detect fallback need --------
__global__ __launch_bounds__(256) void k_scan1a(unsigned* scalU, const unsigned* __restrict__ h16)
{
  __shared__ unsigned hsum[2048];
  __shared__ unsigned sscan[256];
  __shared__ int s_b; __shared__ unsigned s_cnt;
  int t = threadIdx.x;
  for (int j = t; j < 2048; j += 256) {
    unsigned s = 0;
#pragma unroll
    for (int r = 0; r < NREP; ++r) s += h16[r * 2048 + j];
    hsum[j] = s;
  }
  if (t == 0) { s_b = 0; s_cnt = 0; }
  __syncthreads();
  unsigned p = 0;
  for (int j = 508 + t; j < 2048; j += 256) p += hsum[j];
  unsigned total = bsumu(p, sscan);
  if (total >= TOPK_TOTAL) {
    findBin(hsum, 2048, TOPK_TOTAL, 0u, sscan, &s_b, &s_cnt);
    if (t == 0) { scalU[0] = (unsigned)s_b; scalU[1] = s_cnt; scalU[13] = 0u; }
  } else if (t == 0) scalU[13] = 1u;
}

// -------- fallback: full positive histogram (normally immediate-return) --------
__global__ __launch_bounds__(256) void k_histfull(const float4* __restrict__ a4,
    const unsigned* __restrict__ scalU, unsigned* __restrict__ h16)
{
  if (scalU[13] == 0u) return;
  __shared__ unsigned lh[4][2048];
  for (int j = threadIdx.x; j < 8192; j += 256) ((unsigned*)lh)[j] = 0;
  __syncthreads();
  unsigned* mylh = lh[threadIdx.x & 3];
  int stride = gridDim.x * blockDim.x;
  for (int i = blockIdx.x * 256 + threadIdx.x; i < NDI / 4; i += stride) {
    float4 f = a4[i];
    if (f.x > 0.f) atomicAdd(&mylh[__float_as_uint(f.x) >> 21], 1u);
    if (f.y > 0.f) atomicAdd(&mylh[__float_as_uint(f.y) >> 21], 1u);
    if (f.z > 0.f) atomicAdd(&mylh[__float_as_uint(f.z) >> 21], 1u);
    if (f.w > 0.f) atomicAdd(&mylh[__float_as_uint(f.w) >> 21], 1u);
  }
  __syncthreads();
  unsigned* dst = h16 + (size_t)(blockIdx.x & (NREP - 1)) * 2048;
  for (int j = threadIdx.x; j < 2048; j += 256) {
    unsigned c = lh[0][j] + lh[1][j] + lh[2][j] + lh[3][j];
    if (c) atomicAdd(&dst[j], c);
  }
}

__global__ __launch_bounds__(256) void k_scan1b(unsigned* scalU, const unsigned* __restrict__ h16)
{
  if (scalU[13] == 0u) return;
  __shared__ unsigned hsum[2048];
  __shared__ unsigned sscan[256];
  __shared__ int s_b; __shared__ unsigned s_cnt;
  int t = threadIdx.x;
  for (int j = t; j < 2048; j += 256) {
    unsigned s = 0;
#pragma unroll
    for (int r = 0; r < NREP; ++r) s += h16[r * 2048 + j];
    hsum[j] = s;
  }
  if (t == 0) { s_b = 0; s_cnt = 0; }
  __syncthreads();
  findBin(hsum, 2048, TOPK_TOTAL, 0u, sscan, &s_b, &s_cnt);
  if (t == 0) { scalU[0] = (unsigned)s_b; scalU[1] = s_cnt; }
}

// -------- compact candidates (bin >= b1), block-aggregated --------
__global__ __launch_bounds__(256) void k_compact(const float4* __restrict__ a4,
    unsigned* scalU, unsigned* __restrict__ candI, float* __restrict__ candV)
{
  __shared__ unsigned sIdx[CSTAGE];
  __shared__ float sVal[CSTAGE];
  __shared__ unsigned sCnt, sBase;
  if (threadIdx.x == 0) sCnt = 0;
  __syncthreads();
  unsigned b1 = scalU[0];
  int stride = gridDim.x * blockDim.x;
  for (int i = blockIdx.x * 256 + threadIdx.x; i < NDI / 4; i += stride) {
    float4 f = a4[i];
    float vv[4] = {f.x, f.y, f.z, f.w};
#pragma unroll
    for (int c = 0; c < 4; ++c) {
      float v = vv[c];
      if (v > 0.f && (__float_as_uint(v) >> 21) >= b1) {
        unsigned p = atomicAdd(&sCnt, 1u);
        if (p < (unsigned)CSTAGE) { sIdx[p] = (unsigned)(i * 4 + c); sVal[p] = v; }
        else {
          unsigned g = atomicAdd(&scalU[12], 1u);
          if (g < (unsigned)CANDCAP) { candI[g] = (unsigned)(i * 4 + c); candV[g] = v; }
        }
      }
    }
  }
  __syncthreads();
  unsigned n = sCnt < (unsigned)CSTAGE ? sCnt : (unsigned)CSTAGE;
  if (threadIdx.x == 0) sBase = atomicAdd(&scalU[12], n);
  __syncthreads();
  unsigned base = sBase;
  for (unsigned j = threadIdx.x; j < n; j += 256) {
    unsigned g = base + j;
    if (g < (unsigned)CANDCAP) { candI[g] = sIdx[j]; candV[g] = sVal[j]; }
  }
}

// -------- refine level 2: multi-block histogram over candidates --------
__global__ __launch_bounds__(256) void k_rhist2(const unsigned* __restrict__ scalU,
    const float* __restrict__ candV, unsigned* __restrict__ h16)
{
  __shared__ unsigned lh[2048];
  for (int j = threadIdx.x; j < 2048; j += 256) lh[j] = 0;
  __syncthreads();
  unsigned b1 = scalU[0];
  int n = (int)scalU[12]; if (n > CANDCAP) n = CANDCAP;
  int stride = gridDim.x * blockDim.x;
  for (int j = blockIdx.x * 256 + threadIdx.x; j < n; j += stride) {
    unsigned u = __float_as_uint(candV[j]);
    if ((u >> 21) == b1) atomicAdd(&lh[(u >> 10) & 0x7FFu], 1u);
  }
  __syncthreads();
  unsigned* dst = h16 + (size_t)(blockIdx.x & (NREP - 1)) * 2048;
  for (int j = threadIdx.x; j < 2048; j += 256) {
    unsigned c = lh[j];
    if (c) atomicAdd(&dst[j], c);
  }
}

__global__ __launch_bounds__(256) void k_rscan2(unsigned* scalU, const unsigned* __restrict__ h16)
{
  __shared__ unsigned hsum[2048];
  __shared__ unsigned sscan[256];
  __shared__ int s_b; __shared__ unsigned s_cnt;
  int t = threadIdx.x;
  for (int j = t; j < 2048; j += 256) {
    unsigned s = 0;
#pragma unroll
    for (int r = 0; r < NREP; ++r) s += h16[r * 2048 + j];
    hsum[j] = s;
  }
  if (t == 0) { s_b = 0; s_cnt = 0; }
  __syncthreads();
  findBin(hsum, 2048, TOPK_TOTAL, scalU[1], sscan, &s_b, &s_cnt);
  if (t == 0) { scalU[2] = (unsigned)s_b; scalU[3] = s_cnt; }
}

// -------- refine level 3 --------
__global__ __launch_bounds__(256) void k_rhist3(const unsigned* __restrict__ scalU,
    const float* __restrict__ candV, unsigned* __restrict__ h16)
{
  __shared__ unsigned lh[1024];
  for (int j = threadIdx.x; j < 1024; j += 256) lh[j] = 0;
  __syncthreads();
  unsigned b1 = scalU[0], b2 = scalU[2];
  int n = (int)scalU[12]; if (n > CANDCAP) n = CANDCAP;
  int stride = gridDim.x * blockDim.x;
  for (int j = blockIdx.x * 256 + threadIdx.x; j < n; j += stride) {
    unsigned u = __float_as_uint(candV[j]);
    if ((u >> 21) == b1 && ((u >> 10) & 0x7FFu) == b2) atomicAdd(&lh[u & 0x3FFu], 1u);
  }
  __syncthreads();
  unsigned* dst = h16 + (size_t)(blockIdx.x & (NREP - 1)) * 1024;
  for (int j = threadIdx.x; j < 1024; j += 256) {
    unsigned c = lh[j];
    if (c) atomicAdd(&dst[j], c);
  }
}

__global__ __launch_bounds__(256) void k_rscan3(unsigned* scalU, const unsigned* __restrict__ h16)
{
  __shared__ unsigned hsum[1024];
  __shared__ unsigned sscan[256];
  __shared__ int s_b; __shared__ unsigned s_cnt;
  int t = threadIdx.x;
  for (int j = t; j < 1024; j += 256) {
    unsigned s = 0;
#pragma unroll
    for (int r = 0; r < NREP; ++r) s += h16[r * 1024 + j];
    hsum[j] = s;
  }
  if (t == 0) { s_b = 0; s_cnt = 0; }
  __syncthreads();
  findBin(hsum, 1024, TOPK_TOTAL, scalU[3], sscan, &s_b, &s_cnt);
  if (t == 0) {
    unsigned cut = (scalU[0] << 21) | (scalU[2] << 10) | (unsigned)s_b;
    scalU[4] = cut; scalU[5] = s_cnt; scalU[6] = TOPK_TOTAL - s_cnt;
  }
}

// -------- tie collection (multi-block) + resolve (tiny single-block) --------
__global__ __launch_bounds__(256) void k_tiecol(unsigned* scalU,
    const unsigned* __restrict__ candI, const float* __restrict__ candV,
    unsigned* __restrict__ tieB)
{
  unsigned cut = scalU[4];
  int n = (int)scalU[12]; if (n > CANDCAP) n = CANDCAP;
  int stride = gridDim.x * blockDim.x;
  for (int j = blockIdx.x * 256 + threadIdx.x; j < n; j += stride) {
    if (__float_as_uint(candV[j]) == cut) {
      unsigned p = atomicAdd(&scalU[14], 1u);
      if (p < (unsigned)TIECAP) tieB[p] = candI[j];
    }
  }
}

__global__ __launch_bounds__(256) void k_tieres(unsigned* scalU, const unsigned* __restrict__ tieB)
{
  __shared__ unsigned tbuf[TIECAP];
  __shared__ int sthr;
  int t = threadIdx.x;
  int m = (int)scalU[14]; if (m > TIECAP) m = TIECAP;
  int need = (int)scalU[6];
  for (int j = t; j < m; j += 256) tbuf[j] = tieB[j];
  if (t == 0) sthr = 0x7FFFFFFF;
  __syncthreads();
  if (need < m) {
    for (int ci = t; ci < m; ci += 256) {
      unsigned me = tbuf[ci];
      int r = 0;
      for (int j = 0; j < m; ++j) r += (tbuf[j] < me) ? 1 : 0;
      if (r == need - 1) sthr = (int)me;
    }
  }
  __syncthreads();
  if (t == 0) scalU[7] = (unsigned)sthr;
}

// -------- selection over candidates: per-row lists, col flags, l1/l0 --------
__global__ __launch_bounds__(256) void k_s1b(unsigned* scalU,
    const unsigned* __restrict__ candI, const float* __restrict__ candV,
    unsigned* rowCnt, unsigned* rlc, float* rlv, unsigned* colAct, double* scalD)
{
  __shared__ float redf[256];
  __shared__ unsigned redu[256];
  unsigned cut = scalU[4]; int tthr = (int)scalU[7];
  int n = (int)scalU[12]; if (n > CANDCAP) n = CANDCAP;
  float l1 = 0.f; unsigned l0 = 0;
  int stride = gridDim.x * blockDim.x;
  for (int j = blockIdx.x * 256 + threadIdx.x; j < n; j += stride) {
    float v = candV[j];
    unsigned u = __float_as_uint(v);
    unsigned idx = candI[j];
    if (u > cut || (u == cut && (int)idx <= tthr)) {
      int row = (int)(idx >> 15), col = (int)(idx & (D - 1));
      unsigned slot = atomicAdd(&rowCnt[row], 1u);
      if (slot < ROWCAP) {
        rlc[(size_t)row * ROWCAP + slot] = (unsigned)col;
        rlv[(size_t)row * ROWCAP + slot] = v;
      }
      colAct[col] = 1u;
      l1 += v; l0++;
    }
  }
  float l1s = bsumf(l1, redf);
  unsigned l0s = bsumu(l0, redu);
  if (threadIdx.x == 0) { atomicAdd(&scalD[0], (double)l1s); atomicAdd(&scalU[9], l0s); }
}

// -------- scatter selected into zeroed acts_topk --------
__global__ __launch_bounds__(256) void k_scatter(const unsigned* __restrict__ scalU,
    const unsigned* __restrict__ candI, const float* __restrict__ candV, float* __restrict__ acts)
{
  unsigned cut = scalU[4]; int tthr = (int)scalU[7];
  int n = (int)scalU[12]; if (n > CANDCAP) n = CANDCAP;
  int stride = gridDim.x * blockDim.x;
  for (int j = blockIdx.x * 256 + threadIdx.x; j < n; j += stride) {
    float v = candV[j];
    unsigned u = __float_as_uint(v);
    unsigned idx = candI[j];
    if (u > cut || (u == cut && (int)idx <= tthr)) acts[idx] = v;
  }
}

// -------- dead-column bitmask + num_dead_features --------
__global__ __launch_bounds__(256) void k_dead(const unsigned* __restrict__ colAct,
    const float* __restrict__ nbna, unsigned* deadCols, unsigned* scalU,
    u64* __restrict__ dmask, unsigned* __restrict__ dbase)
{
  __shared__ unsigned scan[256];
  __shared__ unsigned svd;
  const int t = threadIdx.x;
  if (t == 0) svd = 0;
  __syncthreads();
  const int c0 = t * 128;
  u64 w0 = 0, w1 = 0;
  unsigned vd = 0;
  for (int i = 0; i < 64; ++i) {
    int c = c0 + i;
    bool act = colAct[c] != 0;
    float f = nbna[c] + 1.0f;
    if (!act && f >= 5.0f) w0 |= (1ull << i);
    vd += (!act && f > 5.0f) ? 1u : 0u;
  }
  for (int i = 0; i < 64; ++i) {
    int c = c0 + 64 + i;
    bool act = colAct[c] != 0;
    float f = nbna[c] + 1.0f;
    if (!act && f >= 5.0f) w1 |= (1ull << i);
    vd += (!act && f > 5.0f) ? 1u : 0u;
  }
  unsigned cnt = (unsigned)(__popcll(w0) + __popcll(w1));
  scan[t] = cnt; __syncthreads();
  for (int o = 1; o < 256; o <<= 1) {
    unsigned xx = (t >= o) ? scan[t - o] : 0u; __syncthreads();
    scan[t] += xx; __syncthreads();
  }
  unsigned p = scan[t] - cnt;
  dmask[2 * t] = w0; dmask[2 * t + 1] = w1;
  dbase[2 * t] = p; dbase[2 * t + 1] = p + (unsigned)__popcll(w0);
  atomicAdd(&svd, vd);
  __syncthreads();
  if (t == 255) scalU[10] = scan[255];
  if (t == 0) scalU[11] = svd;
  (void)deadCols;
}

// -------- per-row aux top-512: 2 streaming passes + LDS boundary-bin refine --------
__global__ __launch_bounds__(256) void k_auxsel(const float* __restrict__ acts,
    const unsigned* __restrict__ scalU, const u64* __restrict__ dmask,
    unsigned* auxC, float* auxV, unsigned* auxN)
{
  __shared__ u64 smask[512];           // 4 KB
  __shared__ unsigned hist[2048];      // 8 KB
  __shared__ unsigned sscan[256];      // 1 KB
  __shared__ float tval[SCAP];         // 12 KB
  __shared__ unsigned tcol[SCAP];      // 12 KB
  __shared__ int s_b; __shared__ unsigned s_cnt;
  __shared__ unsigned s_sel, s_tm;
  const int row = blockIdx.x, t = threadIdx.x;
  const float4* arow4 = (const float4*)(acts + (size_t)row * D);

  for (int j = t; j < 512; j += 256) smask[j] = dmask[j];
  for (int j = t; j < 2048; j += 256) hist[j] = 0;
  if (t == 0) { s_sel = 0; s_tm = 0; s_b = 0; s_cnt = 0; }
  __syncthreads();

  // pass 1: positive count + level-1 (11-bit) histogram
  unsigned pcnt = 0;
  for (int j = t; j < D / 4; j += 256) {
    float4 f = arow4[j];
    u64 w = smask[j >> 4];
    int sh = (j & 15) * 4;
    float vv[4] = {f.x, f.y, f.z, f.w};
#pragma unroll
    for (int c = 0; c < 4; ++c) {
      if (((w >> (sh + c)) & 1ull) && vv[c] > 0.f) {
        pcnt++;
        atomicAdd(&hist[__float_as_uint(vv[c]) >> 21], 1u);
      }
    }
  }
  unsigned P = bsumu(pcnt, sscan);
  unsigned* outC = auxC + (size_t)row * TOPK_AUX;
  float* outV = auxV + (size_t)row * TOPK_AUX;

  if (P <= (unsigned)TOPK_AUX) {
    for (int j = t; j < D / 4; j += 256) {
      float4 f = arow4[j];
      u64 w = smask[j >> 4];
      int sh = (j & 15) * 4;
      float vv[4] = {f.x, f.y, f.z, f.w};
#pragma unroll
      for (int c = 0; c < 4; ++c)
        if (((w >> (sh + c)) & 1ull) && vv[c] > 0.f) {
          unsigned s = atomicAdd(&s_sel, 1u);
          outC[s] = (unsigned)(j * 4 + c); outV[s] = vv[c];
        }
    }
    __syncthreads();
    if (t == 0) auxN[row] = s_sel;
    return;
  }

  __syncthreads();
  findBin(hist, 2048, (unsigned)TOPK_AUX, 0u, sscan, &s_b, &s_cnt);
  unsigned b1 = (unsigned)s_b, c1 = s_cnt;

  // pass 2: bin > b1 -> emit; bin == b1 -> stage to LDS
  for (int j = t; j < D / 4; j += 256) {
    float4 f = arow4[j];
    u64 w = smask[j >> 4];
    int sh = (j & 15) * 4;
    float vv[4] = {f.x, f.y, f.z, f.w};
#pragma unroll
    for (int c = 0; c < 4; ++c) {
      if (((w >> (sh + c)) & 1ull) && vv[c] > 0.f) {
        unsigned bin = __float_as_uint(vv[c]) >> 21;
        if (bin > b1) {
          unsigned s = atomicAdd(&s_sel, 1u);
          outC[s] = (unsigned)(j * 4 + c); outV[s] = vv[c];
        } else if (bin == b1) {
          unsigned p = atomicAdd(&s_tm, 1u);
          if (p < (unsigned)SCAP) { tcol[p] = (unsigned)(j * 4 + c); tval[p] = vv[c]; }
        }
      }
    }
  }
  __syncthreads();
  int m = (int)s_tm;

  if (m <= SCAP) {
    for (int j = t; j < 2048; j += 256) hist[j] = 0;
    if (t == 0) { s_b = 0; s_cnt = 0; }
    __syncthreads();
    for (int j = t; j < m; j += 256)
      atomicAdd(&hist[(__float_as_uint(tval[j]) >> 10) & 0x7FFu], 1u);
    __syncthreads();
    findBin(hist, 2048, (unsigned)TOPK_AUX, c1, sscan, &s_b, &s_cnt);
    unsigned b2 = (unsigned)s_b, c2 = s_cnt;
    for (int j = t; j < 1024; j += 256) hist[j] = 0;
    if (t == 0) { s_b = 0; s_cnt = 0; }
    __syncthreads();
    for (int j = t; j < m; j += 256) {
      unsigned u = __float_as_uint(tval[j]);
      if (((u >> 10) & 0x7FFu) == b2) atomicAdd(&hist[u & 0x3FFu], 1u);
    }
    __syncthreads();
    findBin(hist, 1024, (unsigned)TOPK_AUX, c2, sscan, &s_b, &s_cnt);
    unsigned cut = (b1 << 21) | (b2 << 10) | (unsigned)s_b;
    int need = TOPK_AUX - (int)s_cnt;
    for (int j = t; j < m; j += 256) {
      unsigned u = __float_as_uint(tval[j]);
      if (u > cut) {
        unsigned s = atomicAdd(&s_sel, 1u);
        outC[s] = tcol[j]; outV[s] = tval[j];
      } else if (u == cut) {
        unsigned col = tcol[j];
        int r = 0;
        for (int k = 0; k < m; ++k)
          r += (__float_as_uint(tval[k]) == cut && tcol[k] < col) ? 1 : 0;
        if (r < need) { unsigned s = atomicAdd(&s_sel, 1u); outC[s] = col; outV[s] = tval[j]; }
      }
    }
    __syncthreads();
    if (t == 0) auxN[row] = s_sel;
    return;
  }

  // ---- fallback (staged overflow): global streaming refine, exact ----
  for (int j = t; j < 2048; j += 256) hist[j] = 0;
  if (t == 0) { s_b = 0; s_cnt = 0; }
  __syncthreads();
  for (int j = t; j < D / 4; j += 256) {
    float4 f = arow4[j];
    u64 w = smask[j >> 4];
    int sh = (j & 15) * 4;
    float vv[4] = {f.x, f.y, f.z, f.w};
#pragma unroll
    for (int c = 0; c < 4; ++c) {
      if (((w >> (sh + c)) & 1ull) && vv[c] > 0.f) {
        unsigned u = __float_as_uint(vv[c]);
        if ((u >> 21) == b1) atomicAdd(&hist[(u >> 10) & 0x7FFu], 1u);
      }
    }
  }
  __syncthreads();
  findBin(hist, 2048, (unsigned)TOPK_AUX, c1, sscan, &s_b, &s_cnt);
  unsigned b2 = (unsigned)s_b, c2 = s_cnt;
  for (int j = t; j < 1024; j += 256) hist[j] = 0;
  if (t == 0) { s_b = 0; s_cnt = 0; }
  __syncthreads();
  unsigned hi21 = (b1 << 11) | b2;
  for (int j = t; j < D / 4; j += 256) {
    float4 f = arow4[j];
    u64 w = smask[j >> 4];
    int sh = (j & 15) * 4;
    float vv[4] = {f.x, f.y, f.z, f.w};
#pragma unroll
    for (int c = 0; c < 4; ++c) {
      if (((w >> (sh + c)) & 1ull) && vv[c] > 0.f) {
        unsigned u = __float_as_uint(vv[c]);
        if ((u >> 10) == hi21) atomicAdd(&hist[u & 0x3FFu], 1u);
      }
    }
  }
  __syncthreads();
  findBin(hist, 1024, (unsigned)TOPK_AUX, c2, sscan, &s_b, &s_cnt);
  unsigned cut = (b1 << 21) | (b2 << 10) | (unsigned)s_b;
  int need = TOPK_AUX - (int)s_cnt;
  if (t == 0) s_tm = 0;
  __syncthreads();
  for (int j = t; j < D / 4; j += 256) {
    float4 f = arow4[j];
    u64 w = smask[j >> 4];
    int sh = (j & 15) * 4;
    float vv[4] = {f.x, f.y, f.z, f.w};
#pragma unroll
    for (int c = 0; c < 4; ++c) {
      if (((w >> (sh + c)) & 1ull) && vv[c] > 0.f) {
        unsigned u = __float_as_uint(vv[c]);
        if (u > cut && (u >> 21) == b1) {
          unsigned s = atomicAdd(&s_sel, 1u);
          outC[s] = (unsigned)(j * 4 + c); outV[s] = vv[c];
        } else if (u == cut) {
          unsigned p = atomicAdd(&s_tm, 1u);
          if (p < (unsigned)SCAP) tcol[p] = (unsigned)(j * 4 + c);
        }
      }
    }
  }
  __syncthreads();
  int mm = (int)s_tm; if (mm > SCAP) mm = SCAP;
  float cv = __uint_as_float(cut);
  for (int ci = t; ci < mm; ci += 256) {
    unsigned col = tcol[ci];
    int r = 0;
    for (int j = 0; j < mm; ++j) r += (tcol[j] < col) ? 1 : 0;
    if (r < need) { unsigned s = atomicAdd(&s_sel, 1u); outC[s] = col; outV[s] = cv; }
  }
  __syncthreads();
  if (t == 0) auxN[row] = s_sel;
}

// -------- sparse matryoshka decode (bf16 Wdec, u32 paired loads, 384 threads) --------
__global__ __launch_bounds__(384) void k_decode(const u16* __restrict__ Wdecb,
    const float* __restrict__ bdec, const float* __restrict__ xn,
    const unsigned* __restrict__ rowCnt, const unsigned* __restrict__ rlc,
    const float* __restrict__ rlv, const float* __restrict__ rmean,
    const float* __restrict__ rstd, float* __restrict__ sae,
    float* __restrict__ resid, double* scalD)
{
  __shared__ int tlc[ROWCAP]; __shared__ float tlv[ROWCAP];
  __shared__ int slc[ROWCAP]; __shared__ float slv[ROWCAP];
  __shared__ int gcnt[5], gpos[5], gend[5];
  __shared__ float red[512];
  const int row = blockIdx.x, t = threadIdx.x;
  int cnt = (int)rowCnt[row]; if (cnt > ROWCAP) cnt = ROWCAP;
  if (t < 5) gcnt[t] = 0;
  __syncthreads();
  for (int e = t; e < cnt; e += 384) {
    int c = (int)rlc[(size_t)row * ROWCAP + e];
    tlc[e] = c; tlv[e] = rlv[(size_t)row * ROWCAP + e];
    int ilog = 31 - __clz(c | 1);
    int g = ilog > 10 ? ilog - 10 : 0;
    atomicAdd(&gcnt[g], 1);
  }
  __syncthreads();
  if (t == 0) {
    int b = 0;
    for (int g = 0; g < 5; ++g) { gpos[g] = b; b += gcnt[g]; gend[g] = b; }
  }
  __syncthreads();
  for (int e = t; e < cnt; e += 384) {
    int c = tlc[e];
    int ilog = 31 - __clz(c | 1);
    int g = ilog > 10 ? ilog - 10 : 0;
    int p = atomicAdd(&gpos[g], 1);
    slc[p] = c; slv[p] = tlv[e];
  }
  __syncthreads();
  float2 r01 = ((const float2*)bdec)[t];
  size_t o = (size_t)row * DIN;
  float2 x01 = ((const float2*)(xn + o))[t];
  int e = 0;
#pragma unroll 1
  for (int g = 0; g < 5; ++g) {
    int e1 = gend[g];
#pragma unroll 2
    for (; e < e1; ++e) {
      int c = slc[e]; float v = slv[e];
      unsigned wv = *(const unsigned*)(Wdecb + (size_t)c * DIN + 2 * t);
      r01.x = fmaf(v, b2f((u16)(wv & 0xFFFFu)), r01.x);
      r01.y = fmaf(v, b2f((u16)(wv >> 16)), r01.y);
    }
    float dd0 = r01.x - x01.x, dd1 = r01.y - x01.y;
    float sq = bsumf2(dd0 * dd0 + dd1 * dd1, red);
    if (t == 0) atomicAdd(&scalD[4 + g], (double)sq);
  }
  float m = rmean[row], sd = rstd[row];
  float2 sv; sv.x = r01.x * sd + m; sv.y = r01.y * sd + m;
  ((float2*)(sae + o))[t] = sv;
  float2 rv; rv.x = x01.x - r01.x; rv.y = x01.y - r01.y;
  ((float2*)(resid + o))[t] = rv;
}

// -------- aux decode (bf16 Wdec, u32 paired loads, 384 threads) + aux MSE --------
__global__ __launch_bounds__(384) void k_auxdec(const u16* __restrict__ Wdecb,
    const unsigned* __restrict__ auxC, const float* __restrict__ auxV,
    const unsigned* __restrict__ auxN, const float* __restrict__ resid, double* scalD)
{
  __shared__ int lc[TOPK_AUX]; __shared__ float lv[TOPK_AUX];
  __shared__ float red[512];
  const int row = blockIdx.x, t = threadIdx.x;
  int cnt = (int)auxN[row]; if (cnt > TOPK_AUX) cnt = TOPK_AUX;
  for (int e = t; e < cnt; e += 384) {
    lc[e] = (int)auxC[(size_t)row * TOPK_AUX + e];
    lv[e] = auxV[(size_t)row * TOPK_AUX + e];
  }
  __syncthreads();
  float a0 = 0.f, a1 = 0.f;
#pragma unroll 4
  for (int e = 0; e < cnt; ++e) {
    int c = lc[e]; float v = lv[e];
    unsigned wv = *(const unsigned*)(Wdecb + (size_t)c * DIN + 2 * t);
    a0 = fmaf(v, b2f((u16)(wv & 0xFFFFu)), a0);
    a1 = fmaf(v, b2f((u16)(wv >> 16)), a1);
  }
  size_t o = (size_t)row * DIN;
  float2 s01 = ((const float2*)(resid + o))[t];
  float d0 = a0 - s01.x, d1 = a1 - s01.y;
  float sq = bsumf2(d0 * d0 + d1 * d1, red);
  float ab = bsumf2(fabsf(a0) + fabsf(a1), red);
  if (t == 0) { atomicAdd(&scalD[9], (double)sq); atomicAdd(&scalD[10], (double)ab); }
}

// -------- scalar finalize --------
__global__ void k_final(const unsigned* __restrict__ scalU, const double* __restrict__ scalD,
                        const float* __restrict__ thr, float* __restrict__ out)
{
  if (threadIdx.x != 0 || blockIdx.x != 0) return;
  const double NEL = (double)B * (double)DIN;
  double term0 = scalD[3] / NEL;
  double tot = term0;
  double mn = 1e300, mx = -1e300;
  for (int g = 0; g < 5; ++g) {
    double l2 = scalD[4 + g] / NEL;
    tot += l2;
    mn = l2 < mn ? l2 : mn;
    mx = l2 > mx ? l2 : mx;
  }
  double mean_l2 = tot / 6.0;
  double sum = scalD[1], ssq = scalD[2];
  double xvar = (ssq - sum * sum / NEL) / (NEL - 1.0);
  double fvu = mean_l2 / (xvar + 1e-10);
  double l1n = scalD[0] / (double)B;
  double l1loss = (double)0.0003f * l1n;
  double l0n = (double)scalU[9] / (double)B;
  double auxmse = scalD[9] / NEL;
  double auxloss = (scalD[10] > 0.0) ? 0.03125 * auxmse : 0.0;
  double loss = mean_l2 + l1loss + auxloss;
  float cutv = __uint_as_float(scalU[4]);
  float t0 = thr[0];
  float newthr = (scalU[9] > 0u) ? (0.99f * t0 + 0.01f * cutv) : t0;
  float* s = out + (size_t)B * DIN + (size_t)NDI;
  s[0] = (float)loss;   s[1] = (float)l1loss; s[2] = (float)mean_l2;
  s[3] = (float)mn;     s[4] = (float)mx;     s[5] = (float)l0n;
  s[6] = (float)l1n;    s[7] = (float)auxloss; s[8] = newthr;
  s[9] = (float)fvu;    s[10] = (float)scalU[11];
}

extern "C" void kernel_launch(void* const* d_in, const int* in_sizes, int n_in,
                              void* d_out, int out_size, void* d_ws, size_t ws_size,
                              hipStream_t stream)
{
  (void)in_sizes; (void)n_in; (void)out_size; (void)ws_size;
  const float* x    = (const float*)d_in[0];
  const float* Wenc = (const float*)d_in[1];
  const float* Wdec = (const float*)d_in[2];
  const float* bdec = (const float*)d_in[3];
  const float* nbna = (const float*)d_in[4];
  const float* thr  = (const float*)d_in[5];
  float* out = (float*)d_out;
  char* ws = (char*)d_ws;

  float* sae  = out;
  float* acts = out + (size_t)B * DIN;   // acts / acts_topk live in the output region

  unsigned* hist1 = (unsigned*)(ws + OFF_HIST1);
  unsigned* hist2 = (unsigned*)(ws + OFF_HIST2);
  unsigned* hist3 = (unsigned*)(ws + OFF_HIST3);
  unsigned* hist4 = (unsigned*)(ws + OFF_HIST4);
  unsigned* scalU = (unsigned*)(ws + OFF_SCALU);
  double*   scalD = (double*)(ws + OFF_SCALD);
  unsigned* rowCnt= (unsigned*)(ws + OFF_ROWCNT);
  unsigned* auxN  = (unsigned*)(ws + OFF_AUXCNT);
  unsigned* colAct= (unsigned*)(ws + OFF_COLACT);
  float* xn    = (float*)(ws + OFF_XN);
  float* resid = (float*)(ws + OFF_RES);
  float* rmean = (float*)(ws + OFF_RMEAN);
  float* rstd  = (float*)(ws + OFF_RSTD);
  u16*   xncb  = (u16*)(ws + OFF_XNCB);
  unsigned* deadC = (unsigned*)(ws + OFF_DEAD);
  u64*      dmask = (u64*)(ws + OFF_DMASK);
  unsigned* dbase = (unsigned*)(ws + OFF_DBASE);
  unsigned* rlc = (unsigned*)(ws + OFF_RLC);
  float*    rlv = (float*)(ws + OFF_RLV);
  unsigned* auxC = (unsigned*)(ws + OFF_AXC);
  float*    auxV = (float*)(ws + OFF_AXV);
  unsigned* candI = (unsigned*)(ws + OFF_CANDI);
  float*    candV = (float*)(ws + OFF_CANDV);
  unsigned* tieB  = (unsigned*)(ws + OFF_TIEB);
  u16* Wt    = (u16*)(ws + OFF_WT);   // WencT bf16, later reused as Wdec bf16
  u16* Wdecb = (u16*)(ws + OFF_WT);

  hipMemsetAsync(ws, 0, ZERO_BYTES, stream);
  hipLaunchKernelGGL(k_rowstats, dim3(B), dim3(256), 0, stream, x, bdec, xn, xncb, rmean, rstd, scalD);
  hipLaunchKernelGGL(k_wt, dim3(D / 64, DIN / 64), dim3(256), 0, stream, Wenc, Wt);
  hipLaunchKernelGGL(k_gemm, dim3(D / 128, B / 128), dim3(256), 0, stream, xncb, Wt, acts, hist1);
  hipLaunchKernelGGL(k_scan1a, dim3(1), dim3(256), 0, stream, scalU, hist1);
  hipLaunchKernelGGL(k_histfull, dim3(2048), dim3(256), 0, stream, (const float4*)acts, scalU, hist2);
  hipLaunchKernelGGL(k_scan1b, dim3(1), dim3(256), 0, stream, scalU, hist2);
  hipLaunchKernelGGL(k_wdecb, dim3(2048), dim3(256), 0, stream, (const float4*)Wdec, Wdecb);
  hipLaunchKernelGGL(k_compact, dim3(2048), dim3(256), 0, stream, (const float4*)acts, scalU, candI, candV);
  hipLaunchKernelGGL(k_rhist2, dim3(256), dim3(256), 0, stream, scalU, candV, hist3);
  hipLaunchKernelGGL(k_rscan2, dim3(1), dim3(256), 0, stream, scalU, hist3);
  hipLaunchKernelGGL(k_rhist3, dim3(256), dim3(256), 0, stream, scalU, candV, hist4);
  hipLaunchKernelGGL(k_rscan3, dim3(1), dim3(256), 0, stream, scalU, hist4);
  hipLaunchKernelGGL(k_tiecol, dim3(256), dim3(256), 0, stream, scalU, candI, candV, tieB);
  hipLaunchKernelGGL(k_tieres, dim3(1), dim3(256), 0, stream, scalU, tieB);
  hipLaunchKernelGGL(k_s1b, dim3(256), dim3(256), 0, stream, scalU, candI, candV, rowCnt, rlc, rlv, colAct, scalD);
  hipLaunchKernelGGL(k_dead, dim3(1), dim3(256), 0, stream, colAct, nbna, deadC, scalU, dmask, dbase);
  hipLaunchKernelGGL(k_auxsel, dim3(B), dim3(256), 0, stream, acts, scalU, dmask, auxC, auxV, auxN);
  hipMemsetAsync(acts, 0, (size_t)NDI * 4, stream);
  hipLaunchKernelGGL(k_scatter, dim3(256), dim3(256), 0, stream, scalU, candI, candV, acts);
  hipLaunchKernelGGL(k_decode, dim3(B), dim3(384), 0, stream, Wdecb, bdec, xn, rowCnt, rlc, rlv, rmean, rstd, sae, resid, scalD);
  hipLaunchKernelGGL(k_auxdec, dim3(B), dim3(384), 0, stream, Wdecb, auxC, auxV, auxN, resid, scalD);
  hipLaunchKernelGGL(k_final, dim3(1), dim3(64), 0, stream, scalU, scalD, thr, out);
}